// Round 6
// baseline (553.971 us; speedup 1.0000x reference)
//
#include <hip/hip_runtime.h>

typedef unsigned short ushort_t;
typedef unsigned int uint_t;
typedef unsigned long long u64_t;

#define Bn 4
#define IND 64
#define Cn 128
#define Nn 4096           // H*W
#define CN 524288         // C*N per batch
#define BUF 2097152       // B*C*N elements per buffer

typedef __attribute__((ext_vector_type(8))) __bf16 bf16x8;
typedef __attribute__((ext_vector_type(4))) float f32x4;

__device__ __forceinline__ float b2f(ushort_t s) {
    return __uint_as_float(((uint_t)s) << 16);
}
__device__ __forceinline__ ushort_t f2b(float f) {
    uint_t u = __float_as_uint(f);
    uint_t r = u + 0x7fffu + ((u >> 16) & 1u);
    return (ushort_t)(r >> 16);
}
__device__ __forceinline__ void unpack8(uint4 u, float* f) {
    f[0] = __uint_as_float(u.x << 16); f[1] = __uint_as_float(u.x & 0xffff0000u);
    f[2] = __uint_as_float(u.y << 16); f[3] = __uint_as_float(u.y & 0xffff0000u);
    f[4] = __uint_as_float(u.z << 16); f[5] = __uint_as_float(u.z & 0xffff0000u);
    f[6] = __uint_as_float(u.w << 16); f[7] = __uint_as_float(u.w & 0xffff0000u);
}
__device__ __forceinline__ float lrelu(float x) { return x >= 0.f ? x : 0.01f * x; }

__device__ __forceinline__ float getv(const float* p, size_t i) { return p[i]; }
__device__ __forceinline__ float getv(const ushort_t* p, size_t i) { return b2f(p[i]); }
__device__ __forceinline__ float4 get4(const float* p, size_t i) { return *(const float4*)(p + i); }
__device__ __forceinline__ float4 get4(const ushort_t* p, size_t i) {
    ushort4 u = *(const ushort4*)(p + i);
    float4 f = {b2f(u.x), b2f(u.y), b2f(u.z), b2f(u.w)};
    return f;
}
__device__ __forceinline__ void stv(float* p, float v) { *p = v; }
__device__ __forceinline__ void stv(ushort_t* p, float v) { *p = f2b(v); }

__device__ __forceinline__ uint4 pack8(float4 a, float4 b) {
    uint4 r;
    r.x = (uint_t)f2b(a.x) | ((uint_t)f2b(a.y) << 16);
    r.y = (uint_t)f2b(a.z) | ((uint_t)f2b(a.w) << 16);
    r.z = (uint_t)f2b(b.x) | ((uint_t)f2b(b.y) << 16);
    r.w = (uint_t)f2b(b.z) | ((uint_t)f2b(b.w) << 16);
    return r;
}

// ---------------- dtype detect ----------------
__global__ void detect_kernel(const void* g1, int* flag) {
    if (threadIdx.x == 0 && blockIdx.x == 0)
        *flag = (((const ushort_t*)g1)[0] == 0x3F80) ? 0 : 1;
}

// ---------------- weight transform: ext (co,ci,3,3) -> bf16 [co][tap][ci] ----------------
template <int CI>
__global__ __launch_bounds__(256) void wtrans(const void* w, ushort_t* Wt, const int* flagp) {
    int F = *flagp;
    int idx = blockIdx.x * 256 + threadIdx.x;
    if (idx >= 128 * 9 * CI) return;
    int co = idx / (9 * CI);
    int rem = idx - co * 9 * CI;
    int tap = rem / CI;
    int ci = rem - tap * CI;
    size_t srci = (size_t)co * CI * 9 + (size_t)ci * 9 + tap;
    float v = F ? ((const float*)w)[srci] : b2f(((const ushort_t*)w)[srci]);
    Wt[idx] = f2b(v);
}

// ---------------- input transpose: ext (b,64,n) -> bf16 (b,n,64) ----------------
template <typename TEXT>
__device__ __forceinline__ void tin_body(const TEXT* src, ushort_t* dst, float (*tile)[33]) {
    int b = blockIdx.z, c0 = blockIdx.y * 32, n0 = blockIdx.x * 32;
    int nx = threadIdx.x & 31, cy = threadIdx.x >> 5;
    #pragma unroll
    for (int s = 0; s < 4; s++) {
        int cl = cy + s * 8;
        tile[cl][nx] = getv(src, ((size_t)(b * 64 + c0 + cl)) * 4096 + n0 + nx);
    }
    __syncthreads();
    #pragma unroll
    for (int s = 0; s < 4; s++) {
        int nl = cy + s * 8;
        dst[((size_t)b * 4096 + n0 + nl) * 64 + c0 + nx] = f2b(tile[nx][nl]);
    }
}

__global__ __launch_bounds__(256) void transpose_in(const void* src, ushort_t* dst, const int* flagp) {
    __shared__ float tile[32][33];
    int F = *flagp;
    if (F) tin_body((const float*)src, dst, tile);
    else   tin_body((const ushort_t*)src, dst, tile);
}

// ---------------- MFMA conv3x3, pad=1, CO=128 ----------------
template <int CI>
__global__ __launch_bounds__(512, 2) void conv_mfma(const ushort_t* __restrict__ Xt,
                                                    const ushort_t* __restrict__ Wt,
                                                    const void* bias, float* __restrict__ out,
                                                    const int* flagp) {
    constexpr int RS = CI + 8;
    constexpr int SROWS = 195;
    constexpr int SBYTES = SROWS * RS * 2;
    constexpr int OBYTES = 128 * 68 * 4;
    constexpr int SMEM = SBYTES > OBYTES ? SBYTES : OBYTES;
    __shared__ __align__(16) char smem[SMEM];
    ushort_t* S = (ushort_t*)smem;
    float* Ob = (float*)smem;

    int t = threadIdx.x;
    int blk = blockIdx.x;
    int b = blk >> 6, y = blk & 63;
    int n0 = y << 6;

    constexpr int RQ = CI / 8;
    constexpr int CNT = SROWS * RQ;
    for (int i = t; i < CNT; i += 512) {
        int s = i / RQ;
        int c8 = (i - s * RQ) * 8;
        int tok = n0 + s - 65;
        uint4 v = {0u, 0u, 0u, 0u};
        if (s < 194 && (unsigned)tok < 4096u)
            v = *(const uint4*)(Xt + ((size_t)b * 4096 + tok) * CI + c8);
        *(uint4*)(S + (size_t)s * RS + c8) = v;
    }
    __syncthreads();

    int lane = t & 63, w = t >> 6;
    int li = lane & 15, q = lane >> 4;
    int px0 = 16 * (w & 3);
    int coh = 64 * (w >> 2);
    int x = px0 + li;

    f32x4 acc[4];
    #pragma unroll
    for (int T = 0; T < 4; T++) acc[T] = {0.f, 0.f, 0.f, 0.f};

    #pragma unroll
    for (int tap = 0; tap < 9; tap++) {
        int dy = tap / 3 - 1, dx = tap % 3 - 1;
        bool vx = (unsigned)(x + dx) < 64u;
        int srow = x + dy * 64 + dx + 65;
        int sr2 = vx ? srow : 194;
        #pragma unroll
        for (int ks = 0; ks < CI / 32; ks++) {
            bf16x8 a = *(const bf16x8*)(S + (size_t)sr2 * RS + ks * 32 + q * 8);
            #pragma unroll
            for (int T = 0; T < 4; T++) {
                int co = coh + 16 * T + li;
                bf16x8 bb = *(const bf16x8*)(Wt + ((size_t)co * 9 + tap) * CI + ks * 32 + q * 8);
                acc[T] = __builtin_amdgcn_mfma_f32_16x16x32_bf16(a, bb, acc[T], 0, 0, 0);
            }
        }
    }
    __syncthreads();

    int F = *flagp;
    #pragma unroll
    for (int T = 0; T < 4; T++) {
        int co = coh + 16 * T + li;
        float bv = F ? ((const float*)bias)[co] : b2f(((const ushort_t*)bias)[co]);
        #pragma unroll
        for (int rr = 0; rr < 4; rr++)
            Ob[(size_t)co * 68 + px0 + 4 * q + rr] = acc[T][rr] + bv;
    }
    __syncthreads();
    for (int i = t; i < 2048; i += 512) {
        int co = i >> 4, p4 = (i & 15) * 4;
        *(uint4*)(out + ((size_t)(b * 128 + co)) * 4096 + n0 + p4) =
            *(const uint4*)(Ob + (size_t)co * 68 + p4);
    }
}

// ---------------- LayerNorm reductions ----------------
__global__ __launch_bounds__(256) void ln_reduce1(const float* __restrict__ src,
                                                  float* __restrict__ part) {
    int t = threadIdx.x;
    size_t base = (size_t)blockIdx.x * 1024 + t * 4;
    float4 v = *(const float4*)(src + base);
    float s = v.x + v.y + v.z + v.w;
    float q = v.x * v.x + v.y * v.y + v.z * v.z + v.w * v.w;
    for (int off = 32; off > 0; off >>= 1) {
        s += __shfl_down(s, off, 64);
        q += __shfl_down(q, off, 64);
    }
    __shared__ float red[8];
    if ((t & 63) == 0) { red[(t >> 6) * 2] = s; red[(t >> 6) * 2 + 1] = q; }
    __syncthreads();
    if (t == 0) {
        s = red[0] + red[2] + red[4] + red[6];
        q = red[1] + red[3] + red[5] + red[7];
        part[blockIdx.x * 2] = s;
        part[blockIdx.x * 2 + 1] = q;
    }
}

__global__ __launch_bounds__(256) void ln_reduce2(const float* __restrict__ part,
                                                  float* __restrict__ der) {
    int b = blockIdx.x, t = threadIdx.x;
    float s = part[(b * 512 + t) * 2] + part[(b * 512 + 256 + t) * 2];
    float q = part[(b * 512 + t) * 2 + 1] + part[(b * 512 + 256 + t) * 2 + 1];
    for (int off = 32; off > 0; off >>= 1) {
        s += __shfl_down(s, off, 64);
        q += __shfl_down(q, off, 64);
    }
    __shared__ float red[8];
    if ((t & 63) == 0) { red[(t >> 6) * 2] = s; red[(t >> 6) * 2 + 1] = q; }
    __syncthreads();
    if (t == 0) {
        s = red[0] + red[2] + red[4] + red[6];
        q = red[1] + red[3] + red[5] + red[7];
        float mean = s * (1.f / (float)CN);
        float var = q * (1.f / (float)CN) - mean * mean;
        der[b * 2] = mean;
        der[b * 2 + 1] = rsqrtf(var + 1e-5f);
    }
}

// ---------------- LN apply + LeakyReLU ----------------
template <typename TEXT, typename TOD, int HT, int HD>
__device__ __forceinline__ void ln_body(const float* src, const TEXT* g, const TEXT* be,
                                        const float* der, ushort_t* outT, TOD* outD,
                                        float (*tile)[33]) {
    int b = blockIdx.z, c0 = blockIdx.y * 32, n0 = blockIdx.x * 32;
    float mean = der[b * 2], rstd = der[b * 2 + 1];
    int nx = threadIdx.x & 31, cy = threadIdx.x >> 5;
    #pragma unroll
    for (int s = 0; s < 4; s++) {
        int cl = cy + s * 8;
        int c = c0 + cl;
        size_t gi = (size_t)c * Nn + n0 + nx;
        float v = (src[(size_t)b * CN + gi] - mean) * rstd * getv(g, gi) + getv(be, gi);
        v = lrelu(v);
        if (HD) stv(outD + (size_t)b * CN + gi, v);
        tile[cl][nx] = v;
    }
    if (HT) {
        __syncthreads();
        #pragma unroll
        for (int s = 0; s < 4; s++) {
            int nl = cy + s * 8;
            int n = n0 + nl;
            int c = c0 + nx;
            outT[((size_t)b * Nn + n) * Cn + c] = f2b(tile[nx][nl]);
        }
    }
}

template <int HT, int HD, int DEXT>
__global__ __launch_bounds__(256) void ln_apply(const float* src, const void* g, const void* be,
                                                const float* der, ushort_t* outT, void* outD,
                                                long doff, const int* flagp) {
    __shared__ float tile[32][33];
    int F = *flagp;
    if (F) {
        if (DEXT && HD)
            ln_body<float, float, HT, HD>(src, (const float*)g, (const float*)be, der, outT,
                                          ((float*)outD) + doff, tile);
        else
            ln_body<float, ushort_t, HT, HD>(src, (const float*)g, (const float*)be, der, outT,
                                             ((ushort_t*)outD) + doff, tile);
    } else {
        ln_body<ushort_t, ushort_t, HT, HD>(src, (const ushort_t*)g, (const ushort_t*)be, der, outT,
                                            ((ushort_t*)outD) + doff, tile);
    }
}

// ---------------- small GEMM (VALU) ----------------
template <int ACT, int TRANS, typename TA, typename TW, typename TO>
__device__ __forceinline__ void gemm_body(const TA* A, const TW* W, const TW* bias, TO* out,
                                          int M, int K, int Rper,
                                          float (*As)[68], float (*Bs)[68]) {
    int m0 = blockIdx.x << 6, r0 = blockIdx.y << 6;
    int t = threadIdx.x, tx = t & 15, ty = t >> 4;
    int sr = t >> 2, sk = (t & 3) << 2;
    float acc[4][4] = {{0.f}};
    for (int kt = 0; kt < K; kt += 16) {
        float4 av = get4(A, (size_t)(r0 + sr) * K + kt + sk);
        float4 wv = get4(W, (size_t)(m0 + sr) * K + kt + sk);
        As[sk + 0][sr] = av.x; As[sk + 1][sr] = av.y;
        As[sk + 2][sr] = av.z; As[sk + 3][sr] = av.w;
        Bs[sk + 0][sr] = wv.x; Bs[sk + 1][sr] = wv.y;
        Bs[sk + 2][sr] = wv.z; Bs[sk + 3][sr] = wv.w;
        __syncthreads();
        #pragma unroll
        for (int kk = 0; kk < 16; kk++) {
            float4 a4 = *(const float4*)&As[kk][ty << 2];
            float4 b4 = *(const float4*)&Bs[kk][tx << 2];
            float aa[4] = {a4.x, a4.y, a4.z, a4.w};
            float bb[4] = {b4.x, b4.y, b4.z, b4.w};
            #pragma unroll
            for (int ii = 0; ii < 4; ii++)
                #pragma unroll
                for (int jj = 0; jj < 4; jj++)
                    acc[ii][jj] += aa[ii] * bb[jj];
        }
        __syncthreads();
    }
    float bv[4];
    #pragma unroll
    for (int jj = 0; jj < 4; jj++) bv[jj] = getv(bias, m0 + (tx << 2) + jj);
    #pragma unroll
    for (int ii = 0; ii < 4; ii++) {
        int r = r0 + (ty << 2) + ii;
        float v[4];
        #pragma unroll
        for (int jj = 0; jj < 4; jj++) {
            float x = acc[ii][jj] + bv[jj];
            if (ACT) x = lrelu(x);
            v[jj] = x;
        }
        if (TRANS) {
            int rb = r / Rper, ri = r % Rper;
            #pragma unroll
            for (int jj = 0; jj < 4; jj++) {
                int m = m0 + (tx << 2) + jj;
                stv(out + ((size_t)rb * M + m) * Rper + ri, v[jj]);
            }
        } else {
            #pragma unroll
            for (int jj = 0; jj < 4; jj++)
                stv(out + (size_t)r * M + m0 + (tx << 2) + jj, v[jj]);
        }
    }
}

template <int ACT, int TRANS, int AK, typename TO>
__global__ __launch_bounds__(256) void gemm_nt(const void* A, long aoff, const void* W,
                                               const void* bias, TO* out, int M, int K, int Rper,
                                               const int* flagp) {
    __shared__ float As[16][68];
    __shared__ float Bs[16][68];
    int F = *flagp;
    if (AK == 0) {
        if (F) gemm_body<ACT, TRANS>((const ushort_t*)A + aoff, (const float*)W, (const float*)bias, out, M, K, Rper, As, Bs);
        else   gemm_body<ACT, TRANS>((const ushort_t*)A + aoff, (const ushort_t*)W, (const ushort_t*)bias, out, M, K, Rper, As, Bs);
    } else if (AK == 1) {
        if (F) gemm_body<ACT, TRANS>((const float*)A + aoff, (const float*)W, (const float*)bias, out, M, K, Rper, As, Bs);
        else   gemm_body<ACT, TRANS>((const float*)A + aoff, (const ushort_t*)W, (const ushort_t*)bias, out, M, K, Rper, As, Bs);
    } else {
        if (F) gemm_body<ACT, TRANS>((const float*)A + aoff, (const float*)W, (const float*)bias, out, M, K, Rper, As, Bs);
        else   gemm_body<ACT, TRANS>((const ushort_t*)A + aoff, (const ushort_t*)W, (const ushort_t*)bias, out, M, K, Rper, As, Bs);
    }
}

// ---------------- f_i_3 stage 1: out1 (b,c,n) ext -> A' bf16 K-TILED [64 kt][512 r][64 k] ----
// Tiled layout makes each gemm_big4 (rb, kt) A-slice one CONTIGUOUS 16 KB span so staging
// loads are fully wave-coalesced (old [512][4096] layout -> 32 scattered 128 B segments
// per wave-load instruction; see R5 post-mortem).
__global__ __launch_bounds__(256) void a_convert(const void* src, long aoff, ushort_t* dst,
                                                 const int* flagp) {
    int F = *flagp;
    int gid = blockIdx.x * 256 + threadIdx.x;   // 262144 groups of 8 elements
    int r = gid >> 9;                           // 0..511 (row = b*128 + c)
    int n0 = (gid & 511) << 3;                  // 0..4095 step 8
    size_t doff = ((size_t)(n0 >> 6) << 15) + ((size_t)r << 6) + (n0 & 63);
    if (F) {
        const float* s = (const float*)src + aoff + (size_t)r * 4096 + n0;
        *(uint4*)(dst + doff) = pack8(*(const float4*)s, *(const float4*)(s + 4));
    } else {
        const ushort_t* s = (const ushort_t*)src + aoff + (size_t)r * 4096 + n0;
        *(uint4*)(dst + doff) = *(const uint4*)s;
    }
}

// ---------------- f_i_3 stage 2: MFMA GEMM, K-split 2, coalesced staging ----------------
// Tile 128r x 64c, K=2048/split. Grid (64 m, 4 rb, 2 ksl) = 512 blocks = 2/CU, 4 waves.
// A: tiled-layout slice is contiguous -> 4 x uint4/thread, sequential across the wave.
// B (fp32 W3): 16 threads/row x 16 B -> full 64 B cache lines, 4-row contiguous runs.
// LDS stays padded (stride 72) so fragment reads are conflict-free; same MFMA inner loop.
__global__ __launch_bounds__(256, 2) void gemm_big4(const ushort_t* __restrict__ Ap,
                                                    const void* __restrict__ W3,
                                                    float* __restrict__ C0,
                                                    float* __restrict__ C1,
                                                    const int* flagp) {
    // Als [128][72] bf16 (18432 B) + Bls [64][72] bf16 (9216 B); epilogue overlay Ot[128][72] f32
    __shared__ __align__(16) char smem[36864];
    ushort_t* Als = (ushort_t*)smem;
    ushort_t* Bls = (ushort_t*)(smem + 18432);
    float* Ot = (float*)smem;

    int F = *flagp;
    int t = threadIdx.x;
    int m0 = blockIdx.x << 6;
    int rb = blockIdx.y;              // rows rb*128 .. +128
    int ksl = blockIdx.z;             // K split 0/1
    int kbase = ksl << 11;            // 2048 elements

    int lane = t & 63, w = t >> 6;
    int li = lane & 15, q = lane >> 4;
    int wr = w & 1, wc = w >> 1;      // wave tile: rows 64*wr, cols 32*wc

    // A source: tiled A'[kt][512][64]; this block's k-step slice is 16 KB contiguous.
    const ushort_t* Asrc = Ap + (((size_t)ksl * 32) << 15) + ((size_t)rb << 13) + t * 8;
    const float* Wf = (const float*)W3;
    const ushort_t* Wh = (const ushort_t*)W3;
    int brow4 = t >> 4, bcol4 = (t & 15) * 4;   // F=1 staging map (16 thr/row, 16 B each)
    int brow8 = t >> 3, bcol8 = (t & 7) * 8;    // F=0 staging map (8 thr/row, 16 B each)
    int arow = t >> 3;                           // A LDS row group (32 rows/inst)

    f32x4 acc[4][2];
    #pragma unroll
    for (int i = 0; i < 4; i++)
        #pragma unroll
        for (int j = 0; j < 2; j++) acc[i][j] = {0.f, 0.f, 0.f, 0.f};

    {   // stage k-step 0
        #pragma unroll
        for (int i = 0; i < 4; i++) {
            uint4 v = *(const uint4*)(Asrc + i * 2048);
            *(uint4*)(Als + (size_t)(i * 32 + arow) * 72 + bcol8) = v;
        }
        if (F) {
            #pragma unroll
            for (int i = 0; i < 4; i++) {
                int row = i * 16 + brow4;
                float4 wv = *(const float4*)(Wf + (size_t)(m0 + row) * 4096 + kbase + bcol4);
                ushort4 u = {f2b(wv.x), f2b(wv.y), f2b(wv.z), f2b(wv.w)};
                *(ushort4*)(Bls + (size_t)row * 72 + bcol4) = u;
            }
        } else {
            #pragma unroll
            for (int i = 0; i < 2; i++) {
                int row = i * 32 + brow8;
                uint4 v = *(const uint4*)(Wh + (size_t)(m0 + row) * 4096 + kbase + bcol8);
                *(uint4*)(Bls + (size_t)row * 72 + bcol8) = v;
            }
        }
    }
    __syncthreads();

    for (int kt = 0; kt < 2048; kt += 64) {
        uint4 pa[4];
        float4 pbf[4];
        uint4 pbu[2];
        bool pf = kt < 1984;
        if (pf) {
            const ushort_t* As2 = Asrc + ((size_t)(kt + 64) << 9);   // +(kt/64+1)*32768 elems
            #pragma unroll
            for (int i = 0; i < 4; i++) pa[i] = *(const uint4*)(As2 + i * 2048);
            if (F) {
                #pragma unroll
                for (int i = 0; i < 4; i++) {
                    int row = i * 16 + brow4;
                    pbf[i] = *(const float4*)(Wf + (size_t)(m0 + row) * 4096 + kbase + kt + 64 + bcol4);
                }
            } else {
                #pragma unroll
                for (int i = 0; i < 2; i++) {
                    int row = i * 32 + brow8;
                    pbu[i] = *(const uint4*)(Wh + (size_t)(m0 + row) * 4096 + kbase + kt + 64 + bcol8);
                }
            }
        }
        __builtin_amdgcn_s_setprio(1);
        #pragma unroll
        for (int ks = 0; ks < 2; ks++) {
            bf16x8 af[4], bfr[2];
            #pragma unroll
            for (int rf = 0; rf < 4; rf++)
                af[rf] = *(const bf16x8*)(Als + (size_t)(64 * wr + 16 * rf + li) * 72 + ks * 32 + q * 8);
            #pragma unroll
            for (int cf = 0; cf < 2; cf++)
                bfr[cf] = *(const bf16x8*)(Bls + (size_t)(32 * wc + 16 * cf + li) * 72 + ks * 32 + q * 8);
            #pragma unroll
            for (int rf = 0; rf < 4; rf++)
                #pragma unroll
                for (int cf = 0; cf < 2; cf++)
                    acc[rf][cf] = __builtin_amdgcn_mfma_f32_16x16x32_bf16(af[rf], bfr[cf], acc[rf][cf], 0, 0, 0);
        }
        __builtin_amdgcn_s_setprio(0);
        __syncthreads();
        if (pf) {
            #pragma unroll
            for (int i = 0; i < 4; i++)
                *(uint4*)(Als + (size_t)(i * 32 + arow) * 72 + bcol8) = pa[i];
            if (F) {
                #pragma unroll
                for (int i = 0; i < 4; i++) {
                    int row = i * 16 + brow4;
                    ushort4 u = {f2b(pbf[i].x), f2b(pbf[i].y), f2b(pbf[i].z), f2b(pbf[i].w)};
                    *(ushort4*)(Bls + (size_t)row * 72 + bcol4) = u;
                }
            } else {
                #pragma unroll
                for (int i = 0; i < 2; i++)
                    *(uint4*)(Bls + (size_t)(i * 32 + brow8) * 72 + bcol8) = pbu[i];
            }
            __syncthreads();
        }
    }

    // epilogue: acc -> LDS fp32 tile -> coalesced partial write
    #pragma unroll
    for (int rf = 0; rf < 4; rf++)
        #pragma unroll
        for (int cf = 0; cf < 2; cf++)
            #pragma unroll
            for (int rr = 0; rr < 4; rr++)
                Ot[(size_t)(64 * wr + 16 * rf + 4 * q + rr) * 72 + 32 * wc + 16 * cf + li] = acc[rf][cf][rr];
    __syncthreads();
    float* Pc = (ksl == 0 ? C0 : C1) + (size_t)(rb * 128) * 4096;
    for (int g = t; g < 2048; g += 256) {   // float4 units: 128 rows x 16
        int row = g >> 4, c4 = (g & 15) * 4;
        *(float4*)(Pc + (size_t)row * 4096 + m0 + c4) = *(const float4*)(Ot + (size_t)row * 72 + c4);
    }
}

// ---------------- f_i_3 stage 3: merge 2 K-split partials + bias + lrelu -> (b,m,c) bf16 ----------------
__global__ __launch_bounds__(256) void gemm_merge(const float* __restrict__ C0,
                                                  const float* __restrict__ C1,
                                                  const void* b3, ushort_t* __restrict__ out,
                                                  const int* flagp) {
    __shared__ float tile[32][33];
    int F = *flagp;
    int m0 = blockIdx.x * 32, c0 = blockIdx.y * 32, b = blockIdx.z;
    int nx = threadIdx.x & 31, cy = threadIdx.x >> 5;
    float bv = F ? ((const float*)b3)[m0 + nx] : b2f(((const ushort_t*)b3)[m0 + nx]);
    #pragma unroll
    for (int s = 0; s < 4; s++) {
        int cl = cy + s * 8;
        size_t ri = (size_t)(b * 128 + c0 + cl) * 4096 + m0 + nx;
        tile[cl][nx] = lrelu(C0[ri] + C1[ri] + bv);
    }
    __syncthreads();
    #pragma unroll
    for (int s = 0; s < 4; s++) {
        int ml = cy + s * 8;
        out[((size_t)b * 4096 + m0 + ml) * 128 + c0 + nx] = f2b(tile[nx][ml]);
    }
}

// ---------------- MFMA flash attention v3 ----------------
// KV-split 4-way; each block: 128 Q-rows, 16 KV tiles; each WAVE owns 32 Q-rows
// (2 sub-blocks of 16) so every Ks/Vt b128 fragment read feeds 2 MFMAs.
__global__ __launch_bounds__(256, 2) void attn_mfma(const ushort_t* __restrict__ Q,
                                                    const ushort_t* __restrict__ Kg,
                                                    const ushort_t* __restrict__ Vg,
                                                    ushort_t* __restrict__ Op0,
                                                    ushort_t* __restrict__ Op1,
                                                    ushort_t* __restrict__ Op2,
                                                    ushort_t* __restrict__ Op3,
                                                    float* __restrict__ ML) {
    __shared__ __align__(16) ushort_t Ks[64 * 136];
    __shared__ __align__(16) ushort_t Vt[128 * 72];
    __shared__ __align__(16) ushort_t Ps[128 * 88];

    int t = threadIdx.x;
    int blk = blockIdx.x;
    int h = blk >> 7;            // KV split 0..3
    int rblk = blk & 127;
    int b = rblk & 3;
    int qt = rblk >> 2;          // 0..31
    int n0 = qt << 7;            // 128 Q rows per block
    int lane = t & 63, w = t >> 6;
    int li = lane & 15, q = lane >> 4;

    int kj = t >> 2, kc0 = (t & 3) * 32;
    int vd = t >> 1, vk0 = (t & 1) * 32;

    int kt0 = h << 4;            // first KV tile (16 per split)
    int m00 = kt0 << 6;

    {   // stage K first
        const ushort_t* kp = Kg + ((size_t)(b * Nn + m00 + kj)) * 128 + kc0;
        ushort_t* dst = Ks + kj * 136 + kc0;
        #pragma unroll
        for (int cc = 0; cc < 4; cc++)
            *(uint4*)(dst + cc * 8) = *(const uint4*)(kp + cc * 8);
    }
    {   // stage V first
        const ushort_t* vp = Vg + (size_t)b * CN + (size_t)vd * Nn + m00 + vk0;
        ushort_t* dst = Vt + vd * 72 + vk0;
        #pragma unroll
        for (int cc = 0; cc < 4; cc++)
            *(uint4*)(dst + cc * 8) = *(const uint4*)(vp + cc * 8);
    }

    // Q fragments straight from global (one-time; rows 32w+16sub+li)
    bf16x8 qf[2][4];
    #pragma unroll
    for (int sub = 0; sub < 2; sub++)
        #pragma unroll
        for (int ks = 0; ks < 4; ks++)
            qf[sub][ks] = *(const bf16x8*)(Q +
                ((size_t)(b * Nn + n0 + 32 * w + 16 * sub + li)) * 128 + ks * 32 + q * 8);

    f32x4 acc[2][8];
    #pragma unroll
    for (int sub = 0; sub < 2; sub++)
        #pragma unroll
        for (int T = 0; T < 8; T++) acc[sub][T] = {0.f, 0.f, 0.f, 0.f};
    float m_i[2][4], l_i[2][4];   // l_i LANE-PARTIAL (reduced once at the end)
    #pragma unroll
    for (int sub = 0; sub < 2; sub++)
        #pragma unroll
        for (int r = 0; r < 4; r++) { m_i[sub][r] = -1e30f; l_i[sub][r] = 0.f; }

    __syncthreads();

    for (int kt = kt0; kt < kt0 + 16; kt++) {
        uint4 pk[4], pv[4];
        bool pf = kt < kt0 + 15;
        if (pf) {
            int m1 = (kt + 1) << 6;
            const ushort_t* kp = Kg + ((size_t)(b * Nn + m1 + kj)) * 128 + kc0;
            #pragma unroll
            for (int cc = 0; cc < 4; cc++) pk[cc] = *(const uint4*)(kp + cc * 8);
            const ushort_t* vp = Vg + (size_t)b * CN + (size_t)vd * Nn + m1 + vk0;
            #pragma unroll
            for (int cc = 0; cc < 4; cc++) pv[cc] = *(const uint4*)(vp + cc * 8);
        }

        // S = Q . K^T for both sub-blocks; each Ks fragment feeds 2 MFMAs
        f32x4 s[2][4];
        #pragma unroll
        for (int sub = 0; sub < 2; sub++)
            #pragma unroll
            for (int T = 0; T < 4; T++) s[sub][T] = {0.f, 0.f, 0.f, 0.f};
        __builtin_amdgcn_s_setprio(1);
        #pragma unroll
        for (int ks = 0; ks < 4; ks++) {
            bf16x8 a0 = qf[0][ks];
            bf16x8 a1 = qf[1][ks];
            #pragma unroll
            for (int T = 0; T < 4; T++) {
                bf16x8 kb = *(const bf16x8*)(Ks + (16 * T + li) * 136 + ks * 32 + q * 8);
                s[0][T] = __builtin_amdgcn_mfma_f32_16x16x32_bf16(a0, kb, s[0][T], 0, 0, 0);
                s[1][T] = __builtin_amdgcn_mfma_f32_16x16x32_bf16(a1, kb, s[1][T], 0, 0, 0);
            }
        }
        __builtin_amdgcn_s_setprio(0);

        // online softmax, rows (32w + 16sub + 4q + r), wave-local
        float rm[2][4];
        bool grow = false;
        #pragma unroll
        for (int sub = 0; sub < 2; sub++)
            #pragma unroll
            for (int r = 0; r < 4; r++) {
                float v = fmaxf(fmaxf(s[sub][0][r], s[sub][1][r]),
                                fmaxf(s[sub][2][r], s[sub][3][r]));
                v = fmaxf(v, __shfl_xor(v, 1, 64));
                v = fmaxf(v, __shfl_xor(v, 2, 64));
                v = fmaxf(v, __shfl_xor(v, 4, 64));
                v = fmaxf(v, __shfl_xor(v, 8, 64));
                rm[sub][r] = v;
                grow = grow || (v > m_i[sub][r]);
            }
        if (__any(grow)) {
            #pragma unroll
            for (int sub = 0; sub < 2; sub++)
                #pragma unroll
                for (int r = 0; r < 4; r++) {
                    float mnew = fmaxf(m_i[sub][r], rm[sub][r]);
                    float al = __expf(m_i[sub][r] - mnew);
                    m_i[sub][r] = mnew;
                    float rsum = 0.f;
                    #pragma unroll
                    for (int T = 0; T < 4; T++) {
                        float pvv = __expf(s[sub][T][r] - mnew);
                        Ps[(32 * w + 16 * sub + 4 * q + r) * 88 + 16 * T + li] = f2b(pvv);
                        rsum += pvv;
                    }
                    l_i[sub][r] = l_i[sub][r] * al + rsum;
                    #pragma unroll
                    for (int T = 0; T < 8; T++) acc[sub][T][r] *= al;
                }
        } else {
            #pragma unroll
            for (int sub = 0; sub < 2; sub++)
                #pragma unroll
                for (int r = 0; r < 4; r++) {
                    float rsum = 0.f;
                    #pragma unroll
                    for (int T = 0; T < 4; T++) {
                        float pvv = __expf(s[sub][T][r] - m_i[sub][r]);
                        Ps[(32 * w + 16 * sub + 4 * q + r) * 88 + 16 * T + li] = f2b(pvv);
                        rsum += pvv;
                    }
                    l_i[sub][r] += rsum;
                }
        }

        // O += P . V ; each Vt fragment feeds 2 MFMAs
        __builtin_amdgcn_s_setprio(1);
        #pragma unroll
        for (int ks = 0; ks < 2; ks++) {
            bf16x8 pa0 = *(const bf16x8*)(Ps + (32 * w + li) * 88 + ks * 32 + q * 8);
            bf16x8 pa1 = *(const bf16x8*)(Ps + (32 * w + 16 + li) * 88 + ks * 32 + q * 8);
            #pragma unroll
            for (int T = 0; T < 8; T++) {
                bf16x8 vb = *(const bf16x8*)(Vt + (16 * T + li) * 72 + ks * 32 + q * 8);
                acc[0][T] = __builtin_amdgcn_mfma_f32_16x16x32_bf16(pa0, vb, acc[0][T], 0, 0, 0);
                acc[1][T] = __builtin_amdgcn_mfma_f32_16x16x32_bf16(pa1, vb, acc[1][T], 0, 0, 0);
            }
        }
        __builtin_amdgcn_s_setprio(0);
        __syncthreads();
        if (pf) {
            ushort_t* dk = Ks + kj * 136 + kc0;
            #pragma unroll
            for (int cc = 0; cc < 4; cc++) *(uint4*)(dk + cc * 8) = pk[cc];
            ushort_t* dv = Vt + vd * 72 + vk0;
            #pragma unroll
            for (int cc = 0; cc < 4; cc++) *(uint4*)(dv + cc * 8) = pv[cc];
            __syncthreads();
        }
    }

    // reduce lane-partial l across the 16-lane row group (once)
    #pragma unroll
    for (int sub = 0; sub < 2; sub++)
        #pragma unroll
        for (int r = 0; r < 4; r++) {
            float ls = l_i[sub][r];
            ls += __shfl_xor(ls, 1, 64);
            ls += __shfl_xor(ls, 2, 64);
            ls += __shfl_xor(ls, 4, 64);
            ls += __shfl_xor(ls, 8, 64);
            l_i[sub][r] = ls;
        }

    // emit unnormalized partials (bf16) + (m,l)
    ushort_t* Op = (h == 0) ? Op0 : (h == 1) ? Op1 : (h == 2) ? Op2 : Op3;
    #pragma unroll
    for (int sub = 0; sub < 2; sub++)
        #pragma unroll
        for (int T = 0; T < 8; T++)
            #pragma unroll
            for (int r = 0; r < 4; r++) {
                int n = n0 + 32 * w + 16 * sub + 4 * q + r;
                int d = 16 * T + li;
                Op[((size_t)(b * Nn + n)) * 128 + d] = f2b(acc[sub][T][r]);
            }
    if (li == 0) {
        #pragma unroll
        for (int sub = 0; sub < 2; sub++)
            #pragma unroll
            for (int r = 0; r < 4; r++) {
                int n = n0 + 32 * w + 16 * sub + 4 * q + r;
                size_t mi = ((size_t)(h * Bn + b) * Nn + n) * 2;
                ML[mi] = m_i[sub][r];
                ML[mi + 1] = l_i[sub][r];
            }
    }
}

// ---------------- attention merge: combine 4 KV-split partials -> fp32 (b,n,c) ----------------
__global__ __launch_bounds__(256) void attn_merge(const ushort_t* __restrict__ Op0,
                                                  const ushort_t* __restrict__ Op1,
                                                  const ushort_t* __restrict__ Op2,
                                                  const ushort_t* __restrict__ Op3,
                                                  const float* __restrict__ ML,
                                                  float* __restrict__ Og) {
    int idx = blockIdx.x * 256 + threadIdx.x;   // 262144 items: token*16 + c8grp
    int token = idx >> 4;
    int c8 = (idx & 15) * 8;
    float m[4], l[4];
    #pragma unroll
    for (int s = 0; s < 4; s++) {
        m[s] = ML[((size_t)s * (Bn * Nn) + token) * 2];
        l[s] = ML[((size_t)s * (Bn * Nn) + token) * 2 + 1];
    }
    float M = fmaxf(fmaxf(m[0], m[1]), fmaxf(m[2], m[3]));
    float e[4];
    float denom = 0.f;
    #pragma unroll
    for (int s = 0; s < 4; s++) { e[s] = __expf(m[s] - M); denom += l[s] * e[s]; }
    float inv = 1.f / denom;
    #pragma unroll
    for (int s = 0; s < 4; s++) e[s] *= inv;
    uint4 u0 = *(const uint4*)(Op0 + (size_t)token * 128 + c8);
    uint4 u1 = *(const uint4*)(Op1 + (size_t)token * 128 + c8);
    uint4 u2 = *(const uint4*)(Op2 + (size_t)token * 128 + c8);
    uint4 u3 = *(const uint4*)(Op3 + (size_t)token * 128 + c8);
    float f0[8], f1[8], f2[8], f3[8];
    unpack8(u0, f0);
    unpack8(u1, f1);
    unpack8(u2, f2);
    unpack8(u3, f3);
    float o[8];
    #pragma unroll
    for (int j = 0; j < 8; j++)
        o[j] = f0[j] * e[0] + f1[j] * e[1] + f2[j] * e[2] + f3[j] * e[3];
    float4 v0 = {o[0], o[1], o[2], o[3]};
    float4 v1 = {o[4], o[5], o[6], o[7]};
    float* op = Og + (size_t)token * 128 + c8;
    *(float4*)op = v0;
    *(float4*)(op + 4) = v1;
}

// ---------------- final: f_e_8 = conv1x1(f_e_5 * f_i_6, wf) + bf ----------------
template <typename TEXT, typename TOUT>
__device__ __forceinline__ void final_body(const ushort_t* fe5, const ushort_t* fi6t,
                                           const TEXT* wf, const TEXT* bf, TOUT* out0,
                                           float* prod, ushort_t* wfs, float* bfs) {
    int t = threadIdx.x;
    int b = blockIdx.x >> 6;
    int px0 = (blockIdx.x & 63) * 64;
    for (int idx = t * 4; idx < 8192; idx += 1024) {
        float4 v = get4(wf, idx);
        ushort4 u = {f2b(v.x), f2b(v.y), f2b(v.z), f2b(v.w)};
        *(ushort4*)&wfs[idx] = u;
    }
    if (t < 64) bfs[t] = getv(bf, t);
    {
        int pix = t >> 2, kc = (t & 3) * 32;
        const ushort_t* ap = fe5 + ((size_t)(b * Nn + px0 + pix)) * 128 + kc;
        const ushort_t* bp = fi6t + ((size_t)(b * Nn + px0 + pix)) * 128 + kc;
        #pragma unroll
        for (int c = 0; c < 4; c++) {
            uint4 ua = *(const uint4*)(ap + c * 8);
            uint4 ub = *(const uint4*)(bp + c * 8);
            float fa[8], fb[8];
            unpack8(ua, fa);
            unpack8(ub, fb);
            float* pp = &prod[pix * 132 + kc + c * 8];
            #pragma unroll
            for (int j = 0; j < 8; j++) pp[j] = fa[j] * fb[j];
        }
    }
    __syncthreads();
    int pix = t >> 2, og = t & 3;
    for (int k = 0; k < 16; k++) {
        int o = og * 16 + k;
        float a = bfs[o];
        for (int kc = 0; kc < 128; kc += 8) {
            uint4 wu = *(const uint4*)&wfs[o * 128 + kc];
            float w8[8];
            unpack8(wu, w8);
            const float* pp = &prod[pix * 132 + kc];
            float4 p0 = *(const float4*)pp;
            float4 p1 = *(const float4*)(pp + 4);
            a += w8[0] * p0.x + w8[1] * p0.y + w8[2] * p0.z + w8[3] * p0.w
               + w8[4] * p1.x + w8[5] * p1.y + w8[6] * p1.z + w8[7] * p1.w;
        }
        stv(out0 + ((size_t)(b * 64 + o)) * Nn + px0 + pix, a);
    }
}

__global__ __launch_bounds__(256) void final_out(const ushort_t* fe5, const ushort_t* fi6t,
                                                 const void* wf, const void* bf, void* out0,
                                                 const int* flagp) {
    __shared__ __align__(16) float prod[64 * 132];
    __shared__ __align__(16) ushort_t wfs[64 * 128];
    __shared__ float bfs[64];
    int F = *flagp;
    if (F) final_body((const ushort_t*)fe5, fi6t, (const float*)wf, (const float*)bf, (float*)out0, prod, wfs, bfs);
    else   final_body((const ushort_t*)fe5, fi6t, (const ushort_t*)wf, (const ushort_t*)bf, (ushort_t*)out0, prod, wfs, bfs);
}

extern "C" void kernel_launch(void* const* d_in, const int* in_sizes, int n_in,
                              void* d_out, int out_size, void* d_ws, size_t ws_size,
                              hipStream_t stream) {
    const void* f_e = d_in[0];
    const void* f_i = d_in[1];
    const void* w1 = d_in[2];
    const void* b1 = d_in[3];
    const void* g1 = d_in[4];
    const void* be1 = d_in[5];
    const void* w2 = d_in[6];
    const void* b2 = d_in[7];
    const void* g2 = d_in[8];
    const void* be2 = d_in[9];
    const void* W3 = d_in[10];
    const void* b3 = d_in[11];
    const void* W4 = d_in[12];
    const void* b4 = d_in[13];
    const void* W5 = d_in[14];
    const void* b5 = d_in[15];
    const void* w6a = d_in[16];
    const void* b6a = d_in[17];
    const void* g6a = d_in[18];
    const void* be6a = d_in[19];
    const void* w6b = d_in[20];
    const void* b6b = d_in[21];
    const void* g6b = d_in[22];
    const void* be6b = d_in[23];
    const void* wf = d_in[24];
    const void* bf = d_in[25];

    char* wsb = (char*)d_ws;
    int* FLAG = (int*)wsb;
    float* PART = (float*)(wsb + 1024);
    float* DER  = (float*)(wsb + 17408);
    ushort_t* Wt1  = (ushort_t*)(wsb + 32768);
    ushort_t* Wt2  = (ushort_t*)(wsb + 180224);
    ushort_t* Wt6b = (ushort_t*)(wsb + 327680);
    float* ML   = (float*)(wsb + 32768);         // 512 KB (4 splits), reuses dead Wt1/Wt2 at attn time
    float* TMP  = (float*)(wsb + 622592);
    ushort_t* FE1  = (ushort_t*)(wsb + 9011200);
    ushort_t* TOK  = FE1 + BUF;
    ushort_t* FI3T = TOK + BUF;
    ushort_t* FE4  = FI3T + BUF;
    ushort_t* Y6   = FE4 + BUF;
    ushort_t* FI6T = Y6 + BUF;

    ushort_t* FEt = FI3T;
    ushort_t* FIt = FE4;

    // f_i_3 scratch (all dead at gemm_big4 time):
    // fp32 partial chunks [512 r][4096 m]: C0 = TMP (8 MB), C1 = FE4+Y6 (8 MB contiguous);
    // A' bf16 (k-tiled [64][512][64]) in FI6T
    float* C0 = TMP;
    float* C1 = (float*)FE4;
    ushort_t* ABF = FI6T;

    // attention scratch: partials 2/3 in the dead TMP region; merged fp32 output
    // in the dead K/Q buffers (FI3T+FE4, 8 MB contiguous)
    ushort_t* OPA = (ushort_t*)TMP;
    ushort_t* OPB = OPA + BUF;
    float* MRG = (float*)FI3T;

    const long OUT1OFF = (long)Bn * IND * Nn;

    dim3 lnGrid(128, 4, 4);
    dim3 tinGrid(128, 2, 4);

    detect_kernel<<<1, 64, 0, stream>>>(g1, FLAG);

    wtrans<64><<<288, 256, 0, stream>>>(w1, Wt1, FLAG);
    wtrans<64><<<288, 256, 0, stream>>>(w2, Wt2, FLAG);
    wtrans<128><<<576, 256, 0, stream>>>(w6b, Wt6b, FLAG);

    // f_1: transpose -> conv(MFMA) -> LN -> FE1 (b,c,n)
    transpose_in<<<tinGrid, 256, 0, stream>>>(f_e, FEt, FLAG);
    conv_mfma<64><<<256, 512, 0, stream>>>(FEt, Wt1, b1, TMP, FLAG);
    ln_reduce1<<<2048, 256, 0, stream>>>(TMP, PART);
    ln_reduce2<<<4, 256, 0, stream>>>(PART, DER);
    ln_apply<0, 1, 0><<<lnGrid, 256, 0, stream>>>(TMP, g1, be1, DER, nullptr, FE1, 0, FLAG);

    // f_2: transpose -> conv(MFMA) -> LN -> TOK (b,n,c) + out1 (b,c,n ext)
    transpose_in<<<tinGrid, 256, 0, stream>>>(f_i, FIt, FLAG);
    conv_mfma<64><<<256, 512, 0, stream>>>(FIt, Wt2, b2, TMP, FLAG);
    ln_reduce1<<<2048, 256, 0, stream>>>(TMP, PART);
    ln_reduce2<<<4, 256, 0, stream>>>(PART, DER);
    ln_apply<1, 1, 1><<<lnGrid, 256, 0, stream>>>(TMP, g2, be2, DER, TOK, d_out, OUT1OFF, FLAG);

    // f_i_3: convert A -> bf16 (k-tiled), K-split MFMA GEMM (coalesced staging), merge -> FI3T
    a_convert<<<1024, 256, 0, stream>>>(d_out, OUT1OFF, ABF, FLAG);
    gemm_big4<<<dim3(64, 4, 2), 256, 0, stream>>>(ABF, W3, C0, C1, FLAG);
    gemm_merge<<<dim3(128, 4, 4), 256, 0, stream>>>(C0, C1, b3, FI3T, FLAG);

    // f_e_4: TOK -> FE4
    gemm_nt<1, 0, 0, ushort_t><<<dim3(2, 256), 256, 0, stream>>>(TOK, 0, W4, b4, FE4, 128, 128, 1, FLAG);

    // f_6a: conv1x1 -> TMP (b,c,n) -> LN -> Y6 (b,n,c)
    gemm_nt<0, 1, 0, float><<<dim3(2, 256), 256, 0, stream>>>(TOK, 0, w6a, b6a, TMP, 128, 128, 4096, FLAG);
    ln_reduce1<<<2048, 256, 0, stream>>>(TMP, PART);
    ln_reduce2<<<4, 256, 0, stream>>>(PART, DER);
    ln_apply<1, 0, 0><<<lnGrid, 256, 0, stream>>>(TMP, g6a, be6a, DER, Y6, nullptr, 0, FLAG);

    // f_6b: conv(MFMA) -> LN -> FI6T (b,n,c)
    conv_mfma<128><<<256, 512, 0, stream>>>(Y6, Wt6b, b6b, TMP, FLAG);
    ln_reduce1<<<2048, 256, 0, stream>>>(TMP, PART);
    ln_reduce2<<<4, 256, 0, stream>>>(PART, DER);
    ln_apply<1, 0, 0><<<lnGrid, 256, 0, stream>>>(TMP, g6b, be6b, DER, FI6T, nullptr, 0, FLAG);

    // attention: 4-way KV-split partials (TOK, Y6, TMP region — all dead) + ML,
    // then merge -> MRG (fp32, in dead FI3T+FE4)
    attn_mfma<<<512, 256, 0, stream>>>(FE4, FI3T, FE1, TOK, Y6, OPA, OPB, ML);
    attn_merge<<<1024, 256, 0, stream>>>(TOK, Y6, OPA, OPB, ML, MRG);

    // f_e_5: MRG (fp32) -> Y6 (b,n,c) bf16
    gemm_nt<1, 0, 1, ushort_t><<<dim3(2, 256), 256, 0, stream>>>(MRG, 0, W5, b5, Y6, 128, 128, 1, FLAG);

    // final
    final_out<<<256, 256, 0, stream>>>(Y6, FI6T, wf, bf, d_out, FLAG);
}

// Round 8
// 521.725 us; speedup vs baseline: 1.0618x; 1.0618x over previous
//
#include <hip/hip_runtime.h>

typedef unsigned short ushort_t;
typedef unsigned int uint_t;
typedef unsigned long long u64_t;

#define Bn 4
#define IND 64
#define Cn 128
#define Nn 4096           // H*W
#define CN 524288         // C*N per batch
#define BUF 2097152       // B*C*N elements per buffer

typedef __attribute__((ext_vector_type(8))) __bf16 bf16x8;
typedef __attribute__((ext_vector_type(4))) float f32x4;

__device__ __forceinline__ float b2f(ushort_t s) {
    return __uint_as_float(((uint_t)s) << 16);
}
__device__ __forceinline__ ushort_t f2b(float f) {
    uint_t u = __float_as_uint(f);
    uint_t r = u + 0x7fffu + ((u >> 16) & 1u);
    return (ushort_t)(r >> 16);
}
__device__ __forceinline__ void unpack8(uint4 u, float* f) {
    f[0] = __uint_as_float(u.x << 16); f[1] = __uint_as_float(u.x & 0xffff0000u);
    f[2] = __uint_as_float(u.y << 16); f[3] = __uint_as_float(u.y & 0xffff0000u);
    f[4] = __uint_as_float(u.z << 16); f[5] = __uint_as_float(u.z & 0xffff0000u);
    f[6] = __uint_as_float(u.w << 16); f[7] = __uint_as_float(u.w & 0xffff0000u);
}
__device__ __forceinline__ float lrelu(float x) { return x >= 0.f ? x : 0.01f * x; }

__device__ __forceinline__ float getv(const float* p, size_t i) { return p[i]; }
__device__ __forceinline__ float getv(const ushort_t* p, size_t i) { return b2f(p[i]); }
__device__ __forceinline__ float4 get4(const float* p, size_t i) { return *(const float4*)(p + i); }
__device__ __forceinline__ float4 get4(const ushort_t* p, size_t i) {
    ushort4 u = *(const ushort4*)(p + i);
    float4 f = {b2f(u.x), b2f(u.y), b2f(u.z), b2f(u.w)};
    return f;
}
__device__ __forceinline__ void stv(float* p, float v) { *p = v; }
__device__ __forceinline__ void stv(ushort_t* p, float v) { *p = f2b(v); }

__device__ __forceinline__ uint4 pack8(float4 a, float4 b) {
    uint4 r;
    r.x = (uint_t)f2b(a.x) | ((uint_t)f2b(a.y) << 16);
    r.y = (uint_t)f2b(a.z) | ((uint_t)f2b(a.w) << 16);
    r.z = (uint_t)f2b(b.x) | ((uint_t)f2b(b.y) << 16);
    r.w = (uint_t)f2b(b.z) | ((uint_t)f2b(b.w) << 16);
    return r;
}

// ---------------- dtype detect ----------------
__global__ void detect_kernel(const void* g1, int* flag) {
    if (threadIdx.x == 0 && blockIdx.x == 0)
        *flag = (((const ushort_t*)g1)[0] == 0x3F80) ? 0 : 1;
}

// ---------------- weight transform: ext (co,ci,3,3) -> bf16 [co][tap][ci] ----------------
template <int CI>
__global__ __launch_bounds__(256) void wtrans(const void* w, ushort_t* Wt, const int* flagp) {
    int F = *flagp;
    int idx = blockIdx.x * 256 + threadIdx.x;
    if (idx >= 128 * 9 * CI) return;
    int co = idx / (9 * CI);
    int rem = idx - co * 9 * CI;
    int tap = rem / CI;
    int ci = rem - tap * CI;
    size_t srci = (size_t)co * CI * 9 + (size_t)ci * 9 + tap;
    float v = F ? ((const float*)w)[srci] : b2f(((const ushort_t*)w)[srci]);
    Wt[idx] = f2b(v);
}

// ---------------- input transpose: ext (b,64,n) -> bf16 (b,n,64) ----------------
template <typename TEXT>
__device__ __forceinline__ void tin_body(const TEXT* src, ushort_t* dst, float (*tile)[33]) {
    int b = blockIdx.z, c0 = blockIdx.y * 32, n0 = blockIdx.x * 32;
    int nx = threadIdx.x & 31, cy = threadIdx.x >> 5;
    #pragma unroll
    for (int s = 0; s < 4; s++) {
        int cl = cy + s * 8;
        tile[cl][nx] = getv(src, ((size_t)(b * 64 + c0 + cl)) * 4096 + n0 + nx);
    }
    __syncthreads();
    #pragma unroll
    for (int s = 0; s < 4; s++) {
        int nl = cy + s * 8;
        dst[((size_t)b * 4096 + n0 + nl) * 64 + c0 + nx] = f2b(tile[nx][nl]);
    }
}

__global__ __launch_bounds__(256) void transpose_in(const void* src, ushort_t* dst, const int* flagp) {
    __shared__ float tile[32][33];
    int F = *flagp;
    if (F) tin_body((const float*)src, dst, tile);
    else   tin_body((const ushort_t*)src, dst, tile);
}

// ---------------- MFMA conv3x3, pad=1, CO=128 ----------------
template <int CI>
__global__ __launch_bounds__(512, 2) void conv_mfma(const ushort_t* __restrict__ Xt,
                                                    const ushort_t* __restrict__ Wt,
                                                    const void* bias, float* __restrict__ out,
                                                    const int* flagp) {
    constexpr int RS = CI + 8;
    constexpr int SROWS = 195;
    constexpr int SBYTES = SROWS * RS * 2;
    constexpr int OBYTES = 128 * 68 * 4;
    constexpr int SMEM = SBYTES > OBYTES ? SBYTES : OBYTES;
    __shared__ __align__(16) char smem[SMEM];
    ushort_t* S = (ushort_t*)smem;
    float* Ob = (float*)smem;

    int t = threadIdx.x;
    int blk = blockIdx.x;
    int b = blk >> 6, y = blk & 63;
    int n0 = y << 6;

    constexpr int RQ = CI / 8;
    constexpr int CNT = SROWS * RQ;
    for (int i = t; i < CNT; i += 512) {
        int s = i / RQ;
        int c8 = (i - s * RQ) * 8;
        int tok = n0 + s - 65;
        uint4 v = {0u, 0u, 0u, 0u};
        if (s < 194 && (unsigned)tok < 4096u)
            v = *(const uint4*)(Xt + ((size_t)b * 4096 + tok) * CI + c8);
        *(uint4*)(S + (size_t)s * RS + c8) = v;
    }
    __syncthreads();

    int lane = t & 63, w = t >> 6;
    int li = lane & 15, q = lane >> 4;
    int px0 = 16 * (w & 3);
    int coh = 64 * (w >> 2);
    int x = px0 + li;

    f32x4 acc[4];
    #pragma unroll
    for (int T = 0; T < 4; T++) acc[T] = {0.f, 0.f, 0.f, 0.f};

    #pragma unroll
    for (int tap = 0; tap < 9; tap++) {
        int dy = tap / 3 - 1, dx = tap % 3 - 1;
        bool vx = (unsigned)(x + dx) < 64u;
        int srow = x + dy * 64 + dx + 65;
        int sr2 = vx ? srow : 194;
        #pragma unroll
        for (int ks = 0; ks < CI / 32; ks++) {
            bf16x8 a = *(const bf16x8*)(S + (size_t)sr2 * RS + ks * 32 + q * 8);
            #pragma unroll
            for (int T = 0; T < 4; T++) {
                int co = coh + 16 * T + li;
                bf16x8 bb = *(const bf16x8*)(Wt + ((size_t)co * 9 + tap) * CI + ks * 32 + q * 8);
                acc[T] = __builtin_amdgcn_mfma_f32_16x16x32_bf16(a, bb, acc[T], 0, 0, 0);
            }
        }
    }
    __syncthreads();

    int F = *flagp;
    #pragma unroll
    for (int T = 0; T < 4; T++) {
        int co = coh + 16 * T + li;
        float bv = F ? ((const float*)bias)[co] : b2f(((const ushort_t*)bias)[co]);
        #pragma unroll
        for (int rr = 0; rr < 4; rr++)
            Ob[(size_t)co * 68 + px0 + 4 * q + rr] = acc[T][rr] + bv;
    }
    __syncthreads();
    for (int i = t; i < 2048; i += 512) {
        int co = i >> 4, p4 = (i & 15) * 4;
        *(uint4*)(out + ((size_t)(b * 128 + co)) * 4096 + n0 + p4) =
            *(const uint4*)(Ob + (size_t)co * 68 + p4);
    }
}

// ---------------- LayerNorm reductions ----------------
__global__ __launch_bounds__(256) void ln_reduce1(const float* __restrict__ src,
                                                  float* __restrict__ part) {
    int t = threadIdx.x;
    size_t base = (size_t)blockIdx.x * 1024 + t * 4;
    float4 v = *(const float4*)(src + base);
    float s = v.x + v.y + v.z + v.w;
    float q = v.x * v.x + v.y * v.y + v.z * v.z + v.w * v.w;
    for (int off = 32; off > 0; off >>= 1) {
        s += __shfl_down(s, off, 64);
        q += __shfl_down(q, off, 64);
    }
    __shared__ float red[8];
    if ((t & 63) == 0) { red[(t >> 6) * 2] = s; red[(t >> 6) * 2 + 1] = q; }
    __syncthreads();
    if (t == 0) {
        s = red[0] + red[2] + red[4] + red[6];
        q = red[1] + red[3] + red[5] + red[7];
        part[blockIdx.x * 2] = s;
        part[blockIdx.x * 2 + 1] = q;
    }
}

__global__ __launch_bounds__(256) void ln_reduce2(const float* __restrict__ part,
                                                  float* __restrict__ der) {
    int b = blockIdx.x, t = threadIdx.x;
    float s = part[(b * 512 + t) * 2] + part[(b * 512 + 256 + t) * 2];
    float q = part[(b * 512 + t) * 2 + 1] + part[(b * 512 + 256 + t) * 2 + 1];
    for (int off = 32; off > 0; off >>= 1) {
        s += __shfl_down(s, off, 64);
        q += __shfl_down(q, off, 64);
    }
    __shared__ float red[8];
    if ((t & 63) == 0) { red[(t >> 6) * 2] = s; red[(t >> 6) * 2 + 1] = q; }
    __syncthreads();
    if (t == 0) {
        s = red[0] + red[2] + red[4] + red[6];
        q = red[1] + red[3] + red[5] + red[7];
        float mean = s * (1.f / (float)CN);
        float var = q * (1.f / (float)CN) - mean * mean;
        der[b * 2] = mean;
        der[b * 2 + 1] = rsqrtf(var + 1e-5f);
    }
}

// ---------------- LN apply + LeakyReLU ----------------
template <typename TEXT, typename TOD, int HT, int HD>
__device__ __forceinline__ void ln_body(const float* src, const TEXT* g, const TEXT* be,
                                        const float* der, ushort_t* outT, TOD* outD,
                                        float (*tile)[33]) {
    int b = blockIdx.z, c0 = blockIdx.y * 32, n0 = blockIdx.x * 32;
    float mean = der[b * 2], rstd = der[b * 2 + 1];
    int nx = threadIdx.x & 31, cy = threadIdx.x >> 5;
    #pragma unroll
    for (int s = 0; s < 4; s++) {
        int cl = cy + s * 8;
        int c = c0 + cl;
        size_t gi = (size_t)c * Nn + n0 + nx;
        float v = (src[(size_t)b * CN + gi] - mean) * rstd * getv(g, gi) + getv(be, gi);
        v = lrelu(v);
        if (HD) stv(outD + (size_t)b * CN + gi, v);
        tile[cl][nx] = v;
    }
    if (HT) {
        __syncthreads();
        #pragma unroll
        for (int s = 0; s < 4; s++) {
            int nl = cy + s * 8;
            int n = n0 + nl;
            int c = c0 + nx;
            outT[((size_t)b * Nn + n) * Cn + c] = f2b(tile[nx][nl]);
        }
    }
}

template <int HT, int HD, int DEXT>
__global__ __launch_bounds__(256) void ln_apply(const float* src, const void* g, const void* be,
                                                const float* der, ushort_t* outT, void* outD,
                                                long doff, const int* flagp) {
    __shared__ float tile[32][33];
    int F = *flagp;
    if (F) {
        if (DEXT && HD)
            ln_body<float, float, HT, HD>(src, (const float*)g, (const float*)be, der, outT,
                                          ((float*)outD) + doff, tile);
        else
            ln_body<float, ushort_t, HT, HD>(src, (const float*)g, (const float*)be, der, outT,
                                             ((ushort_t*)outD) + doff, tile);
    } else {
        ln_body<ushort_t, ushort_t, HT, HD>(src, (const ushort_t*)g, (const ushort_t*)be, der, outT,
                                            ((ushort_t*)outD) + doff, tile);
    }
}

// ---------------- small GEMM (VALU) ----------------
template <int ACT, int TRANS, typename TA, typename TW, typename TO>
__device__ __forceinline__ void gemm_body(const TA* A, const TW* W, const TW* bias, TO* out,
                                          int M, int K, int Rper,
                                          float (*As)[68], float (*Bs)[68]) {
    int m0 = blockIdx.x << 6, r0 = blockIdx.y << 6;
    int t = threadIdx.x, tx = t & 15, ty = t >> 4;
    int sr = t >> 2, sk = (t & 3) << 2;
    float acc[4][4] = {{0.f}};
    for (int kt = 0; kt < K; kt += 16) {
        float4 av = get4(A, (size_t)(r0 + sr) * K + kt + sk);
        float4 wv = get4(W, (size_t)(m0 + sr) * K + kt + sk);
        As[sk + 0][sr] = av.x; As[sk + 1][sr] = av.y;
        As[sk + 2][sr] = av.z; As[sk + 3][sr] = av.w;
        Bs[sk + 0][sr] = wv.x; Bs[sk + 1][sr] = wv.y;
        Bs[sk + 2][sr] = wv.z; Bs[sk + 3][sr] = wv.w;
        __syncthreads();
        #pragma unroll
        for (int kk = 0; kk < 16; kk++) {
            float4 a4 = *(const float4*)&As[kk][ty << 2];
            float4 b4 = *(const float4*)&Bs[kk][tx << 2];
            float aa[4] = {a4.x, a4.y, a4.z, a4.w};
            float bb[4] = {b4.x, b4.y, b4.z, b4.w};
            #pragma unroll
            for (int ii = 0; ii < 4; ii++)
                #pragma unroll
                for (int jj = 0; jj < 4; jj++)
                    acc[ii][jj] += aa[ii] * bb[jj];
        }
        __syncthreads();
    }
    float bv[4];
    #pragma unroll
    for (int jj = 0; jj < 4; jj++) bv[jj] = getv(bias, m0 + (tx << 2) + jj);
    #pragma unroll
    for (int ii = 0; ii < 4; ii++) {
        int r = r0 + (ty << 2) + ii;
        float v[4];
        #pragma unroll
        for (int jj = 0; jj < 4; jj++) {
            float x = acc[ii][jj] + bv[jj];
            if (ACT) x = lrelu(x);
            v[jj] = x;
        }
        if (TRANS) {
            int rb = r / Rper, ri = r % Rper;
            #pragma unroll
            for (int jj = 0; jj < 4; jj++) {
                int m = m0 + (tx << 2) + jj;
                stv(out + ((size_t)rb * M + m) * Rper + ri, v[jj]);
            }
        } else {
            #pragma unroll
            for (int jj = 0; jj < 4; jj++)
                stv(out + (size_t)r * M + m0 + (tx << 2) + jj, v[jj]);
        }
    }
}

template <int ACT, int TRANS, int AK, typename TO>
__global__ __launch_bounds__(256) void gemm_nt(const void* A, long aoff, const void* W,
                                               const void* bias, TO* out, int M, int K, int Rper,
                                               const int* flagp) {
    __shared__ float As[16][68];
    __shared__ float Bs[16][68];
    int F = *flagp;
    if (AK == 0) {
        if (F) gemm_body<ACT, TRANS>((const ushort_t*)A + aoff, (const float*)W, (const float*)bias, out, M, K, Rper, As, Bs);
        else   gemm_body<ACT, TRANS>((const ushort_t*)A + aoff, (const ushort_t*)W, (const ushort_t*)bias, out, M, K, Rper, As, Bs);
    } else if (AK == 1) {
        if (F) gemm_body<ACT, TRANS>((const float*)A + aoff, (const float*)W, (const float*)bias, out, M, K, Rper, As, Bs);
        else   gemm_body<ACT, TRANS>((const float*)A + aoff, (const ushort_t*)W, (const ushort_t*)bias, out, M, K, Rper, As, Bs);
    } else {
        if (F) gemm_body<ACT, TRANS>((const float*)A + aoff, (const float*)W, (const float*)bias, out, M, K, Rper, As, Bs);
        else   gemm_body<ACT, TRANS>((const ushort_t*)A + aoff, (const ushort_t*)W, (const ushort_t*)bias, out, M, K, Rper, As, Bs);
    }
}

// ---------------- f_i_3 stage 1: out1 -> A' bf16, k-tiled [64 kt][512 r][64 k], PRE-SWIZZLED --
// 16-B granule g within each row is stored at g^(r&7) so gemm_big6 can copy the tile
// LINEARLY with global_load_lds and read fragments with the same XOR (rule #21c:
// linear LDS dest + inverse-swizzled source + swizzled read).
__global__ __launch_bounds__(256) void a_convert(const void* src, long aoff, ushort_t* dst,
                                                 const int* flagp) {
    int F = *flagp;
    int gid = blockIdx.x * 256 + threadIdx.x;   // 262144 groups of 8 elements
    int r = gid >> 9;                           // 0..511 (row = b*128 + c)
    int n0 = (gid & 511) << 3;                  // 0..4095 step 8
    int gs = ((n0 >> 3) & 7) ^ (r & 7);         // swizzled 16-B granule
    size_t doff = ((size_t)(n0 >> 6) << 15) + ((size_t)r << 6) + ((size_t)gs << 3);
    if (F) {
        const float* s = (const float*)src + aoff + (size_t)r * 4096 + n0;
        *(uint4*)(dst + doff) = pack8(*(const float4*)s, *(const float4*)(s + 4));
    } else {
        const ushort_t* s = (const ushort_t*)src + aoff + (size_t)r * 4096 + n0;
        *(uint4*)(dst + doff) = *(const uint4*)s;
    }
}

// ---------------- f_i_3 stage 2: MFMA GEMM via global_load_lds, K-split 4 ----------------
// R3-R6 used register-prefetch arrays (pa[4]/pbf[4]); those were allocated to SCRATCH
// (rule #20 signature: WRITE_SIZE 54-63 MB vs 16 MB actual output since R3; R2 with
// scalar prefetch had clean WRITE) -> ~0.5 GB scratch round-trip dominated the K-loop.
// global_load_lds staging has NO register intermediates at all (m97 structure, 874 TF).
// Tile 128r x 64m, BK=64, K-split 4 -> grid (64,4,4) = 1024 blocks = 4/CU (LDS 32 KB).
// A': identity gl_lds of the pre-swizzled tile. W3: per-lane-source gl_lds (fp32 kept
// in LDS, bf16-converted at fragment read; F=0 input copied as bf16 directly).
// Partials: bf16 [512][4096] per split (error <=0.002 vs 0.03 budget).
// R7 bug (NaN): epilogue used row=idx>>2/c=(idx&3)*8 -> rows 0..255 of a 128-row tile
// (OOB LDS reads + OOB global writes into ABF) and only half the cols. Fixed to >>3/&7.
template <int F>
__device__ __forceinline__ void gemm6_body(const ushort_t* __restrict__ Ap,
                                           const void* __restrict__ W3,
                                           ushort_t* __restrict__ Pc,
                                           char* smem) {
    int t = threadIdx.x;
    int m0 = blockIdx.x << 6;
    int rb = blockIdx.y;
    int ksl = blockIdx.z;
    int lane = t & 63, w = t >> 6;
    int li = lane & 15, q = lane >> 4;
    int wr = w & 1, wc = w >> 1;      // wave tile: rows 64*wr, cols 32*wc
    int kbase = ksl << 10;            // 1024 k-elements per split

    const char* Ab = (const char*)Ap;
    const char* Wb = (const char*)W3;
    size_t Abase = ((size_t)(ksl * 16) << 16) + ((size_t)rb << 14);

    f32x4 acc[4][2];
    #pragma unroll
    for (int i = 0; i < 4; i++)
        #pragma unroll
        for (int j = 0; j < 2; j++) acc[i][j] = {0.f, 0.f, 0.f, 0.f};

    // ---- async staging: no VGPR intermediates ----
    auto stageA = [&](int kt64) {
        size_t tb = Abase + ((size_t)kt64 << 16);
        #pragma unroll
        for (int i = 0; i < 4; i++) {
            int loff = w * 4096 + i * 1024;
            __builtin_amdgcn_global_load_lds(
                (const uint_t*)(Ab + tb + loff + lane * 16),
                (uint_t*)(smem + loff), 16, 0, 0);
        }
    };
    auto stageB = [&](int kt) {
        if (F) {
            #pragma unroll
            for (int i = 0; i < 4; i++) {
                int loff = w * 4096 + i * 1024;
                int L = loff + lane * 16;
                int row = L >> 8, inner = L & 255;
                int sg = (inner >> 5) ^ (row & 7);
                __builtin_amdgcn_global_load_lds(
                    (const uint_t*)(Wb + ((size_t)(m0 + row) << 14) +
                                    (size_t)(kbase + kt) * 4 + (sg << 5) + (inner & 31)),
                    (uint_t*)(smem + 16384 + loff), 16, 0, 0);
            }
        } else {
            #pragma unroll
            for (int i = 0; i < 2; i++) {
                int loff = w * 2048 + i * 1024;
                int L = loff + lane * 16;
                int row = L >> 7, inner = L & 127;
                int sg = (inner >> 4) ^ (row & 7);
                __builtin_amdgcn_global_load_lds(
                    (const uint_t*)(Wb + ((size_t)(m0 + row) << 13) +
                                    (size_t)(kbase + kt) * 2 + (sg << 4)),
                    (uint_t*)(smem + 16384 + loff), 16, 0, 0);
            }
        }
    };

    stageA(0);
    stageB(0);
    for (int it = 0; it < 16; it++) {
        __syncthreads();               // drains own vmcnt (gl_lds landed for all waves)
        const ushort_t* As = (const ushort_t*)smem;
        #pragma unroll
        for (int ks = 0; ks < 2; ks++) {
            int gsw = ks * 4 + q;
            int sw = (gsw ^ (li & 7)) << 3;
            bf16x8 af[4], bfr[2];
            #pragma unroll
            for (int rf = 0; rf < 4; rf++) {
                int row = 64 * wr + 16 * rf + li;
                af[rf] = *(const bf16x8*)(As + row * 64 + sw);
            }
            if (F) {
                const float* Bf = (const float*)(smem + 16384);
                #pragma unroll
                for (int cf = 0; cf < 2; cf++) {
                    int row = 32 * wc + 16 * cf + li;
                    const float* p = Bf + row * 64 + sw;
                    float4 lo = *(const float4*)p;
                    float4 hi = *(const float4*)(p + 4);
                    bf16x8 v;
                    v[0] = (__bf16)lo.x; v[1] = (__bf16)lo.y;
                    v[2] = (__bf16)lo.z; v[3] = (__bf16)lo.w;
                    v[4] = (__bf16)hi.x; v[5] = (__bf16)hi.y;
                    v[6] = (__bf16)hi.z; v[7] = (__bf16)hi.w;
                    bfr[cf] = v;
                }
            } else {
                const ushort_t* Bs = (const ushort_t*)(smem + 16384);
                #pragma unroll
                for (int cf = 0; cf < 2; cf++) {
                    int row = 32 * wc + 16 * cf + li;
                    bfr[cf] = *(const bf16x8*)(Bs + row * 64 + sw);
                }
            }
            #pragma unroll
            for (int rf = 0; rf < 4; rf++)
                #pragma unroll
                for (int cf = 0; cf < 2; cf++)
                    acc[rf][cf] = __builtin_amdgcn_mfma_f32_16x16x32_bf16(af[rf], bfr[cf], acc[rf][cf], 0, 0, 0);
        }
        __syncthreads();               // all reads of this tile done
        if (it < 15) {
            stageA(it + 1);
            stageB((it + 1) << 6);
        }
    }

    // epilogue: acc -> LDS bf16 tile -> coalesced bf16 partial write
    // 128 rows x 64 cols, uint4 = 8 cols/store -> row = idx>>3, c8 = (idx&7)*8
    ushort_t* Ot = (ushort_t*)smem;
    #pragma unroll
    for (int rf = 0; rf < 4; rf++)
        #pragma unroll
        for (int cf = 0; cf < 2; cf++)
            #pragma unroll
            for (int rr = 0; rr < 4; rr++)
                Ot[(64 * wr + 16 * rf + 4 * q + rr) * 72 + 32 * wc + 16 * cf + li] =
                    f2b(acc[rf][cf][rr]);
    __syncthreads();
    #pragma unroll
    for (int i = 0; i < 4; i++) {
        int idx = t + i * 256;
        int row = idx >> 3, c8 = (idx & 7) * 8;
        *(uint4*)(Pc + ((size_t)(rb * 128 + row)) * 4096 + m0 + c8) =
            *(const uint4*)(Ot + row * 72 + c8);
    }
}

__global__ __launch_bounds__(256, 4) void gemm_big6(const ushort_t* __restrict__ Ap,
                                                    const void* __restrict__ W3,
                                                    ushort_t* __restrict__ C0,
                                                    ushort_t* __restrict__ C1,
                                                    ushort_t* __restrict__ C2,
                                                    ushort_t* __restrict__ C3,
                                                    const int* flagp) {
    __shared__ __align__(16) char smem[32768];
    int F = *flagp;
    int ksl = blockIdx.z;
    ushort_t* Pc = (ksl == 0) ? C0 : (ksl == 1) ? C1 : (ksl == 2) ? C2 : C3;
    if (F) gemm6_body<1>(Ap, W3, Pc, smem);
    else   gemm6_body<0>(Ap, W3, Pc, smem);
}

// ---------------- f_i_3 stage 3: merge 4 bf16 K-split partials + bias + lrelu -> (b,m,c) bf16 --
__global__ __launch_bounds__(256) void gemm_merge(const ushort_t* __restrict__ C0,
                                                  const ushort_t* __restrict__ C1,
                                                  const ushort_t* __restrict__ C2,
                                                  const ushort_t* __restrict__ C3,
                                                  const void* b3, ushort_t* __restrict__ out,
                                                  const int* flagp) {
    __shared__ float tile[32][33];
    int F = *flagp;
    int m0 = blockIdx.x * 32, c0 = blockIdx.y * 32, b = blockIdx.z;
    int nx = threadIdx.x & 31, cy = threadIdx.x >> 5;
    float bv = F ? ((const float*)b3)[m0 + nx] : b2f(((const ushort_t*)b3)[m0 + nx]);
    #pragma unroll
    for (int s = 0; s < 4; s++) {
        int cl = cy + s * 8;
        size_t ri = (size_t)(b * 128 + c0 + cl) * 4096 + m0 + nx;
        tile[cl][nx] = lrelu(b2f(C0[ri]) + b2f(C1[ri]) + b2f(C2[ri]) + b2f(C3[ri]) + bv);
    }
    __syncthreads();
    #pragma unroll
    for (int s = 0; s < 4; s++) {
        int ml = cy + s * 8;
        out[((size_t)b * 4096 + m0 + ml) * 128 + c0 + nx] = f2b(tile[nx][ml]);
    }
}

// ---------------- MFMA flash attention v3 ----------------
// KV-split 4-way; each block: 128 Q-rows, 16 KV tiles; each WAVE owns 32 Q-rows
// (2 sub-blocks of 16) so every Ks/Vt b128 fragment read feeds 2 MFMAs.
__global__ __launch_bounds__(256, 2) void attn_mfma(const ushort_t* __restrict__ Q,
                                                    const ushort_t* __restrict__ Kg,
                                                    const ushort_t* __restrict__ Vg,
                                                    ushort_t* __restrict__ Op0,
                                                    ushort_t* __restrict__ Op1,
                                                    ushort_t* __restrict__ Op2,
                                                    ushort_t* __restrict__ Op3,
                                                    float* __restrict__ ML) {
    __shared__ __align__(16) ushort_t Ks[64 * 136];
    __shared__ __align__(16) ushort_t Vt[128 * 72];
    __shared__ __align__(16) ushort_t Ps[128 * 88];

    int t = threadIdx.x;
    int blk = blockIdx.x;
    int h = blk >> 7;            // KV split 0..3
    int rblk = blk & 127;
    int b = rblk & 3;
    int qt = rblk >> 2;          // 0..31
    int n0 = qt << 7;            // 128 Q rows per block
    int lane = t & 63, w = t >> 6;
    int li = lane & 15, q = lane >> 4;

    int kj = t >> 2, kc0 = (t & 3) * 32;
    int vd = t >> 1, vk0 = (t & 1) * 32;

    int kt0 = h << 4;            // first KV tile (16 per split)
    int m00 = kt0 << 6;

    {   // stage K first
        const ushort_t* kp = Kg + ((size_t)(b * Nn + m00 + kj)) * 128 + kc0;
        ushort_t* dst = Ks + kj * 136 + kc0;
        #pragma unroll
        for (int cc = 0; cc < 4; cc++)
            *(uint4*)(dst + cc * 8) = *(const uint4*)(kp + cc * 8);
    }
    {   // stage V first
        const ushort_t* vp = Vg + (size_t)b * CN + (size_t)vd * Nn + m00 + vk0;
        ushort_t* dst = Vt + vd * 72 + vk0;
        #pragma unroll
        for (int cc = 0; cc < 4; cc++)
            *(uint4*)(dst + cc * 8) = *(const uint4*)(vp + cc * 8);
    }

    // Q fragments straight from global (one-time; rows 32w+16sub+li)
    bf16x8 qf[2][4];
    #pragma unroll
    for (int sub = 0; sub < 2; sub++)
        #pragma unroll
        for (int ks = 0; ks < 4; ks++)
            qf[sub][ks] = *(const bf16x8*)(Q +
                ((size_t)(b * Nn + n0 + 32 * w + 16 * sub + li)) * 128 + ks * 32 + q * 8);

    f32x4 acc[2][8];
    #pragma unroll
    for (int sub = 0; sub < 2; sub++)
        #pragma unroll
        for (int T = 0; T < 8; T++) acc[sub][T] = {0.f, 0.f, 0.f, 0.f};
    float m_i[2][4], l_i[2][4];   // l_i LANE-PARTIAL (reduced once at the end)
    #pragma unroll
    for (int sub = 0; sub < 2; sub++)
        #pragma unroll
        for (int r = 0; r < 4; r++) { m_i[sub][r] = -1e30f; l_i[sub][r] = 0.f; }

    __syncthreads();

    for (int kt = kt0; kt < kt0 + 16; kt++) {
        uint4 pk[4], pv[4];
        bool pf = kt < kt0 + 15;
        if (pf) {
            int m1 = (kt + 1) << 6;
            const ushort_t* kp = Kg + ((size_t)(b * Nn + m1 + kj)) * 128 + kc0;
            #pragma unroll
            for (int cc = 0; cc < 4; cc++) pk[cc] = *(const uint4*)(kp + cc * 8);
            const ushort_t* vp = Vg + (size_t)b * CN + (size_t)vd * Nn + m1 + vk0;
            #pragma unroll
            for (int cc = 0; cc < 4; cc++) pv[cc] = *(const uint4*)(vp + cc * 8);
        }

        // S = Q . K^T for both sub-blocks; each Ks fragment feeds 2 MFMAs
        f32x4 s[2][4];
        #pragma unroll
        for (int sub = 0; sub < 2; sub++)
            #pragma unroll
            for (int T = 0; T < 4; T++) s[sub][T] = {0.f, 0.f, 0.f, 0.f};
        __builtin_amdgcn_s_setprio(1);
        #pragma unroll
        for (int ks = 0; ks < 4; ks++) {
            bf16x8 a0 = qf[0][ks];
            bf16x8 a1 = qf[1][ks];
            #pragma unroll
            for (int T = 0; T < 4; T++) {
                bf16x8 kb = *(const bf16x8*)(Ks + (16 * T + li) * 136 + ks * 32 + q * 8);
                s[0][T] = __builtin_amdgcn_mfma_f32_16x16x32_bf16(a0, kb, s[0][T], 0, 0, 0);
                s[1][T] = __builtin_amdgcn_mfma_f32_16x16x32_bf16(a1, kb, s[1][T], 0, 0, 0);
            }
        }
        __builtin_amdgcn_s_setprio(0);

        // online softmax, rows (32w + 16sub + 4q + r), wave-local
        float rm[2][4];
        bool grow = false;
        #pragma unroll
        for (int sub = 0; sub < 2; sub++)
            #pragma unroll
            for (int r = 0; r < 4; r++) {
                float v = fmaxf(fmaxf(s[sub][0][r], s[sub][1][r]),
                                fmaxf(s[sub][2][r], s[sub][3][r]));
                v = fmaxf(v, __shfl_xor(v, 1, 64));
                v = fmaxf(v, __shfl_xor(v, 2, 64));
                v = fmaxf(v, __shfl_xor(v, 4, 64));
                v = fmaxf(v, __shfl_xor(v, 8, 64));
                rm[sub][r] = v;
                grow = grow || (v > m_i[sub][r]);
            }
        if (__any(grow)) {
            #pragma unroll
            for (int sub = 0; sub < 2; sub++)
                #pragma unroll
                for (int r = 0; r < 4; r++) {
                    float mnew = fmaxf(m_i[sub][r], rm[sub][r]);
                    float al = __expf(m_i[sub][r] - mnew);
                    m_i[sub][r] = mnew;
                    float rsum = 0.f;
                    #pragma unroll
                    for (int T = 0; T < 4; T++) {
                        float pvv = __expf(s[sub][T][r] - mnew);
                        Ps[(32 * w + 16 * sub + 4 * q + r) * 88 + 16 * T + li] = f2b(pvv);
                        rsum += pvv;
                    }
                    l_i[sub][r] = l_i[sub][r] * al + rsum;
                    #pragma unroll
                    for (int T = 0; T < 8; T++) acc[sub][T][r] *= al;
                }
        } else {
            #pragma unroll
            for (int sub = 0; sub < 2; sub++)
                #pragma unroll
                for (int r = 0; r < 4; r++) {
                    float rsum = 0.f;
                    #pragma unroll
                    for (int T = 0; T < 4; T++) {
                        float pvv = __expf(s[sub][T][r] - m_i[sub][r]);
                        Ps[(32 * w + 16 * sub + 4 * q + r) * 88 + 16 * T + li] = f2b(pvv);
                        rsum += pvv;
                    }
                    l_i[sub][r] += rsum;
                }
        }

        // O += P . V ; each Vt fragment feeds 2 MFMAs
        __builtin_amdgcn_s_setprio(1);
        #pragma unroll
        for (int ks = 0; ks < 2; ks++) {
            bf16x8 pa0 = *(const bf16x8*)(Ps + (32 * w + li) * 88 + ks * 32 + q * 8);
            bf16x8 pa1 = *(const bf16x8*)(Ps + (32 * w + 16 + li) * 88 + ks * 32 + q * 8);
            #pragma unroll
            for (int T = 0; T < 8; T++) {
                bf16x8 vb = *(const bf16x8*)(Vt + (16 * T + li) * 72 + ks * 32 + q * 8);
                acc[0][T] = __builtin_amdgcn_mfma_f32_16x16x32_bf16(pa0, vb, acc[0][T], 0, 0, 0);
                acc[1][T] = __builtin_amdgcn_mfma_f32_16x16x32_bf16(pa1, vb, acc[1][T], 0, 0, 0);
            }
        }
        __builtin_amdgcn_s_setprio(0);
        __syncthreads();
        if (pf) {
            ushort_t* dk = Ks + kj * 136 + kc0;
            #pragma unroll
            for (int cc = 0; cc < 4; cc++) *(uint4*)(dk + cc * 8) = pk[cc];
            ushort_t* dv = Vt + vd * 72 + vk0;
            #pragma unroll
            for (int cc = 0; cc < 4; cc++) *(uint4*)(dv + cc * 8) = pv[cc];
            __syncthreads();
        }
    }

    // reduce lane-partial l across the 16-lane row group (once)
    #pragma unroll
    for (int sub = 0; sub < 2; sub++)
        #pragma unroll
        for (int r = 0; r < 4; r++) {
            float ls = l_i[sub][r];
            ls += __shfl_xor(ls, 1, 64);
            ls += __shfl_xor(ls, 2, 64);
            ls += __shfl_xor(ls, 4, 64);
            ls += __shfl_xor(ls, 8, 64);
            l_i[sub][r] = ls;
        }

    // emit unnormalized partials (bf16) + (m,l)
    ushort_t* Op = (h == 0) ? Op0 : (h == 1) ? Op1 : (h == 2) ? Op2 : Op3;
    #pragma unroll
    for (int sub = 0; sub < 2; sub++)
        #pragma unroll
        for (int T = 0; T < 8; T++)
            #pragma unroll
            for (int r = 0; r < 4; r++) {
                int n = n0 + 32 * w + 16 * sub + 4 * q + r;
                int d = 16 * T + li;
                Op[((size_t)(b * Nn + n)) * 128 + d] = f2b(acc[sub][T][r]);
            }
    if (li == 0) {
        #pragma unroll
        for (int sub = 0; sub < 2; sub++)
            #pragma unroll
            for (int r = 0; r < 4; r++) {
                int n = n0 + 32 * w + 16 * sub + 4 * q + r;
                size_t mi = ((size_t)(h * Bn + b) * Nn + n) * 2;
                ML[mi] = m_i[sub][r];
                ML[mi + 1] = l_i[sub][r];
            }
    }
}

// ---------------- attention merge: combine 4 KV-split partials -> fp32 (b,n,c) ----------------
__global__ __launch_bounds__(256) void attn_merge(const ushort_t* __restrict__ Op0,
                                                  const ushort_t* __restrict__ Op1,
                                                  const ushort_t* __restrict__ Op2,
                                                  const ushort_t* __restrict__ Op3,
                                                  const float* __restrict__ ML,
                                                  float* __restrict__ Og) {
    int idx = blockIdx.x * 256 + threadIdx.x;   // 262144 items: token*16 + c8grp
    int token = idx >> 4;
    int c8 = (idx & 15) * 8;
    float m[4], l[4];
    #pragma unroll
    for (int s = 0; s < 4; s++) {
        m[s] = ML[((size_t)s * (Bn * Nn) + token) * 2];
        l[s] = ML[((size_t)s * (Bn * Nn) + token) * 2 + 1];
    }
    float M = fmaxf(fmaxf(m[0], m[1]), fmaxf(m[2], m[3]));
    float e[4];
    float denom = 0.f;
    #pragma unroll
    for (int s = 0; s < 4; s++) { e[s] = __expf(m[s] - M); denom += l[s] * e[s]; }
    float inv = 1.f / denom;
    #pragma unroll
    for (int s = 0; s < 4; s++) e[s] *= inv;
    uint4 u0 = *(const uint4*)(Op0 + (size_t)token * 128 + c8);
    uint4 u1 = *(const uint4*)(Op1 + (size_t)token * 128 + c8);
    uint4 u2 = *(const uint4*)(Op2 + (size_t)token * 128 + c8);
    uint4 u3 = *(const uint4*)(Op3 + (size_t)token * 128 + c8);
    float f0[8], f1[8], f2[8], f3[8];
    unpack8(u0, f0);
    unpack8(u1, f1);
    unpack8(u2, f2);
    unpack8(u3, f3);
    float o[8];
    #pragma unroll
    for (int j = 0; j < 8; j++)
        o[j] = f0[j] * e[0] + f1[j] * e[1] + f2[j] * e[2] + f3[j] * e[3];
    float4 v0 = {o[0], o[1], o[2], o[3]};
    float4 v1 = {o[4], o[5], o[6], o[7]};
    float* op = Og + (size_t)token * 128 + c8;
    *(float4*)op = v0;
    *(float4*)(op + 4) = v1;
}

// ---------------- final: f_e_8 = conv1x1(f_e_5 * f_i_6, wf) + bf ----------------
template <typename TEXT, typename TOUT>
__device__ __forceinline__ void final_body(const ushort_t* fe5, const ushort_t* fi6t,
                                           const TEXT* wf, const TEXT* bf, TOUT* out0,
                                           float* prod, ushort_t* wfs, float* bfs) {
    int t = threadIdx.x;
    int b = blockIdx.x >> 6;
    int px0 = (blockIdx.x & 63) * 64;
    for (int idx = t * 4; idx < 8192; idx += 1024) {
        float4 v = get4(wf, idx);
        ushort4 u = {f2b(v.x), f2b(v.y), f2b(v.z), f2b(v.w)};
        *(ushort4*)&wfs[idx] = u;
    }
    if (t < 64) bfs[t] = getv(bf, t);
    {
        int pix = t >> 2, kc = (t & 3) * 32;
        const ushort_t* ap = fe5 + ((size_t)(b * Nn + px0 + pix)) * 128 + kc;
        const ushort_t* bp = fi6t + ((size_t)(b * Nn + px0 + pix)) * 128 + kc;
        #pragma unroll
        for (int c = 0; c < 4; c++) {
            uint4 ua = *(const uint4*)(ap + c * 8);
            uint4 ub = *(const uint4*)(bp + c * 8);
            float fa[8], fb[8];
            unpack8(ua, fa);
            unpack8(ub, fb);
            float* pp = &prod[pix * 132 + kc + c * 8];
            #pragma unroll
            for (int j = 0; j < 8; j++) pp[j] = fa[j] * fb[j];
        }
    }
    __syncthreads();
    int pix = t >> 2, og = t & 3;
    for (int k = 0; k < 16; k++) {
        int o = og * 16 + k;
        float a = bfs[o];
        for (int kc = 0; kc < 128; kc += 8) {
            uint4 wu = *(const uint4*)&wfs[o * 128 + kc];
            float w8[8];
            unpack8(wu, w8);
            const float* pp = &prod[pix * 132 + kc];
            float4 p0 = *(const float4*)pp;
            float4 p1 = *(const float4*)(pp + 4);
            a += w8[0] * p0.x + w8[1] * p0.y + w8[2] * p0.z + w8[3] * p0.w
               + w8[4] * p1.x + w8[5] * p1.y + w8[6] * p1.z + w8[7] * p1.w;
        }
        stv(out0 + ((size_t)(b * 64 + o)) * Nn + px0 + pix, a);
    }
}

__global__ __launch_bounds__(256) void final_out(const ushort_t* fe5, const ushort_t* fi6t,
                                                 const void* wf, const void* bf, void* out0,
                                                 const int* flagp) {
    __shared__ __align__(16) float prod[64 * 132];
    __shared__ __align__(16) ushort_t wfs[64 * 128];
    __shared__ float bfs[64];
    int F = *flagp;
    if (F) final_body((const ushort_t*)fe5, fi6t, (const float*)wf, (const float*)bf, (float*)out0, prod, wfs, bfs);
    else   final_body((const ushort_t*)fe5, fi6t, (const ushort_t*)wf, (const ushort_t*)bf, (ushort_t*)out0, prod, wfs, bfs);
}

extern "C" void kernel_launch(void* const* d_in, const int* in_sizes, int n_in,
                              void* d_out, int out_size, void* d_ws, size_t ws_size,
                              hipStream_t stream) {
    const void* f_e = d_in[0];
    const void* f_i = d_in[1];
    const void* w1 = d_in[2];
    const void* b1 = d_in[3];
    const void* g1 = d_in[4];
    const void* be1 = d_in[5];
    const void* w2 = d_in[6];
    const void* b2 = d_in[7];
    const void* g2 = d_in[8];
    const void* be2 = d_in[9];
    const void* W3 = d_in[10];
    const void* b3 = d_in[11];
    const void* W4 = d_in[12];
    const void* b4 = d_in[13];
    const void* W5 = d_in[14];
    const void* b5 = d_in[15];
    const void* w6a = d_in[16];
    const void* b6a = d_in[17];
    const void* g6a = d_in[18];
    const void* be6a = d_in[19];
    const void* w6b = d_in[20];
    const void* b6b = d_in[21];
    const void* g6b = d_in[22];
    const void* be6b = d_in[23];
    const void* wf = d_in[24];
    const void* bf = d_in[25];

    char* wsb = (char*)d_ws;
    int* FLAG = (int*)wsb;
    float* PART = (float*)(wsb + 1024);
    float* DER  = (float*)(wsb + 17408);
    ushort_t* Wt1  = (ushort_t*)(wsb + 32768);
    ushort_t* Wt2  = (ushort_t*)(wsb + 180224);
    ushort_t* Wt6b = (ushort_t*)(wsb + 327680);
    float* ML   = (float*)(wsb + 32768);         // 512 KB (4 splits), reuses dead Wt1/Wt2 at attn time
    float* TMP  = (float*)(wsb + 622592);
    ushort_t* FE1  = (ushort_t*)(wsb + 9011200);
    ushort_t* TOK  = FE1 + BUF;
    ushort_t* FI3T = TOK + BUF;
    ushort_t* FE4  = FI3T + BUF;
    ushort_t* Y6   = FE4 + BUF;
    ushort_t* FI6T = Y6 + BUF;

    ushort_t* FEt = FI3T;
    ushort_t* FIt = FE4;

    // f_i_3 scratch (all dead at gemm_big6 time):
    // bf16 K-split partials [512 r][4096 m] x4: C0b/C1b in TMP (8 MB), C2b=FE4, C3b=Y6;
    // A' bf16 (k-tiled, pre-swizzled) in FI6T
    ushort_t* C0b = (ushort_t*)TMP;
    ushort_t* C1b = C0b + BUF;
    ushort_t* C2b = FE4;
    ushort_t* C3b = Y6;
    ushort_t* ABF = FI6T;

    // attention scratch: partials 2/3 in the dead TMP region; merged fp32 output
    // in the dead K/Q buffers (FI3T+FE4, 8 MB contiguous)
    ushort_t* OPA = (ushort_t*)TMP;
    ushort_t* OPB = OPA + BUF;
    float* MRG = (float*)FI3T;

    const long OUT1OFF = (long)Bn * IND * Nn;

    dim3 lnGrid(128, 4, 4);
    dim3 tinGrid(128, 2, 4);

    detect_kernel<<<1, 64, 0, stream>>>(g1, FLAG);

    wtrans<64><<<288, 256, 0, stream>>>(w1, Wt1, FLAG);
    wtrans<64><<<288, 256, 0, stream>>>(w2, Wt2, FLAG);
    wtrans<128><<<576, 256, 0, stream>>>(w6b, Wt6b, FLAG);

    // f_1: transpose -> conv(MFMA) -> LN -> FE1 (b,c,n)
    transpose_in<<<tinGrid, 256, 0, stream>>>(f_e, FEt, FLAG);
    conv_mfma<64><<<256, 512, 0, stream>>>(FEt, Wt1, b1, TMP, FLAG);
    ln_reduce1<<<2048, 256, 0, stream>>>(TMP, PART);
    ln_reduce2<<<4, 256, 0, stream>>>(PART, DER);
    ln_apply<0, 1, 0><<<lnGrid, 256, 0, stream>>>(TMP, g1, be1, DER, nullptr, FE1, 0, FLAG);

    // f_2: transpose -> conv(MFMA) -> LN -> TOK (b,n,c) + out1 (b,c,n ext)
    transpose_in<<<tinGrid, 256, 0, stream>>>(f_i, FIt, FLAG);
    conv_mfma<64><<<256, 512, 0, stream>>>(FIt, Wt2, b2, TMP, FLAG);
    ln_reduce1<<<2048, 256, 0, stream>>>(TMP, PART);
    ln_reduce2<<<4, 256, 0, stream>>>(PART, DER);
    ln_apply<1, 1, 1><<<lnGrid, 256, 0, stream>>>(TMP, g2, be2, DER, TOK, d_out, OUT1OFF, FLAG);

    // f_i_3: convert A -> bf16 (k-tiled, pre-swizzled), gl_lds MFMA GEMM (K-split 4,
    // 1024 blocks = 4/CU), merge 4 bf16 partials -> FI3T
    a_convert<<<1024, 256, 0, stream>>>(d_out, OUT1OFF, ABF, FLAG);
    gemm_big6<<<dim3(64, 4, 4), 256, 0, stream>>>(ABF, W3, C0b, C1b, C2b, C3b, FLAG);
    gemm_merge<<<dim3(128, 4, 4), 256, 0, stream>>>(C0b, C1b, C2b, C3b, b3, FI3T, FLAG);

    // f_e_4: TOK -> FE4
    gemm_nt<1, 0, 0, ushort_t><<<dim3(2, 256), 256, 0, stream>>>(TOK, 0, W4, b4, FE4, 128, 128, 1, FLAG);

    // f_6a: conv1x1 -> TMP (b,c,n) -> LN -> Y6 (b,n,c)
    gemm_nt<0, 1, 0, float><<<dim3(2, 256), 256, 0, stream>>>(TOK, 0, w6a, b6a, TMP, 128, 128, 4096, FLAG);
    ln_reduce1<<<2048, 256, 0, stream>>>(TMP, PART);
    ln_reduce2<<<4, 256, 0, stream>>>(PART, DER);
    ln_apply<1, 0, 0><<<lnGrid, 256, 0, stream>>>(TMP, g6a, be6a, DER, Y6, nullptr, 0, FLAG);

    // f_6b: conv(MFMA) -> LN -> FI6T (b,n,c)
    conv_mfma<128><<<256, 512, 0, stream>>>(Y6, Wt6b, b6b, TMP, FLAG);
    ln_reduce1<<<2048, 256, 0, stream>>>(TMP, PART);
    ln_reduce2<<<4, 256, 0, stream>>>(PART, DER);
    ln_apply<1, 0, 0><<<lnGrid, 256, 0, stream>>>(TMP, g6b, be6b, DER, FI6T, nullptr, 0, FLAG);

    // attention: 4-way KV-split partials (TOK, Y6, TMP region — all dead) + ML,
    // then merge -> MRG (fp32, in dead FI3T+FE4)
    attn_mfma<<<512, 256, 0, stream>>>(FE4, FI3T, FE1, TOK, Y6, OPA, OPB, ML);
    attn_merge<<<1024, 256, 0, stream>>>(TOK, Y6, OPA, OPB, ML, MRG);

    // f_e_5: MRG (fp32) -> Y6 (b,n,c) bf16
    gemm_nt<1, 0, 1, ushort_t><<<dim3(2, 256), 256, 0, stream>>>(MRG, 0, W5, b5, Y6, 128, 128, 1, FLAG);

    // final
    final_out<<<256, 256, 0, stream>>>(Y6, FI6T, wf, bf, d_out, FLAG);
}

// Round 9
// 511.141 us; speedup vs baseline: 1.0838x; 1.0207x over previous
//
#include <hip/hip_runtime.h>

typedef unsigned short ushort_t;
typedef unsigned int uint_t;
typedef unsigned long long u64_t;

#define Bn 4
#define IND 64
#define Cn 128
#define Nn 4096           // H*W
#define CN 524288         // C*N per batch
#define BUF 2097152       // B*C*N elements per buffer

typedef __attribute__((ext_vector_type(8))) __bf16 bf16x8;
typedef __attribute__((ext_vector_type(4))) float f32x4;

__device__ __forceinline__ float b2f(ushort_t s) {
    return __uint_as_float(((uint_t)s) << 16);
}
__device__ __forceinline__ ushort_t f2b(float f) {
    uint_t u = __float_as_uint(f);
    uint_t r = u + 0x7fffu + ((u >> 16) & 1u);
    return (ushort_t)(r >> 16);
}
__device__ __forceinline__ void unpack8(uint4 u, float* f) {
    f[0] = __uint_as_float(u.x << 16); f[1] = __uint_as_float(u.x & 0xffff0000u);
    f[2] = __uint_as_float(u.y << 16); f[3] = __uint_as_float(u.y & 0xffff0000u);
    f[4] = __uint_as_float(u.z << 16); f[5] = __uint_as_float(u.z & 0xffff0000u);
    f[6] = __uint_as_float(u.w << 16); f[7] = __uint_as_float(u.w & 0xffff0000u);
}
__device__ __forceinline__ float lrelu(float x) { return x >= 0.f ? x : 0.01f * x; }

__device__ __forceinline__ float getv(const float* p, size_t i) { return p[i]; }
__device__ __forceinline__ float getv(const ushort_t* p, size_t i) { return b2f(p[i]); }
__device__ __forceinline__ float4 get4(const float* p, size_t i) { return *(const float4*)(p + i); }
__device__ __forceinline__ float4 get4(const ushort_t* p, size_t i) {
    ushort4 u = *(const ushort4*)(p + i);
    float4 f = {b2f(u.x), b2f(u.y), b2f(u.z), b2f(u.w)};
    return f;
}
__device__ __forceinline__ void stv(float* p, float v) { *p = v; }
__device__ __forceinline__ void stv(ushort_t* p, float v) { *p = f2b(v); }

__device__ __forceinline__ uint4 pack8(float4 a, float4 b) {
    uint4 r;
    r.x = (uint_t)f2b(a.x) | ((uint_t)f2b(a.y) << 16);
    r.y = (uint_t)f2b(a.z) | ((uint_t)f2b(a.w) << 16);
    r.z = (uint_t)f2b(b.x) | ((uint_t)f2b(b.y) << 16);
    r.w = (uint_t)f2b(b.z) | ((uint_t)f2b(b.w) << 16);
    return r;
}

// ---------------- dtype detect ----------------
__global__ void detect_kernel(const void* g1, int* flag) {
    if (threadIdx.x == 0 && blockIdx.x == 0)
        *flag = (((const ushort_t*)g1)[0] == 0x3F80) ? 0 : 1;
}

// ---------------- weight transform: ext (co,ci,3,3) -> bf16 [co][tap][ci] ----------------
template <int CI>
__global__ __launch_bounds__(256) void wtrans(const void* w, ushort_t* Wt, const int* flagp) {
    int F = *flagp;
    int idx = blockIdx.x * 256 + threadIdx.x;
    if (idx >= 128 * 9 * CI) return;
    int co = idx / (9 * CI);
    int rem = idx - co * 9 * CI;
    int tap = rem / CI;
    int ci = rem - tap * CI;
    size_t srci = (size_t)co * CI * 9 + (size_t)ci * 9 + tap;
    float v = F ? ((const float*)w)[srci] : b2f(((const ushort_t*)w)[srci]);
    Wt[idx] = f2b(v);
}

// ---------------- input transpose: ext (b,64,n) -> bf16 (b,n,64) ----------------
template <typename TEXT>
__device__ __forceinline__ void tin_body(const TEXT* src, ushort_t* dst, float (*tile)[33]) {
    int b = blockIdx.z, c0 = blockIdx.y * 32, n0 = blockIdx.x * 32;
    int nx = threadIdx.x & 31, cy = threadIdx.x >> 5;
    #pragma unroll
    for (int s = 0; s < 4; s++) {
        int cl = cy + s * 8;
        tile[cl][nx] = getv(src, ((size_t)(b * 64 + c0 + cl)) * 4096 + n0 + nx);
    }
    __syncthreads();
    #pragma unroll
    for (int s = 0; s < 4; s++) {
        int nl = cy + s * 8;
        dst[((size_t)b * 4096 + n0 + nl) * 64 + c0 + nx] = f2b(tile[nx][nl]);
    }
}

__global__ __launch_bounds__(256) void transpose_in(const void* src, ushort_t* dst, const int* flagp) {
    __shared__ float tile[32][33];
    int F = *flagp;
    if (F) tin_body((const float*)src, dst, tile);
    else   tin_body((const ushort_t*)src, dst, tile);
}

// ---------------- MFMA conv3x3, pad=1, CO=128 ----------------
template <int CI>
__global__ __launch_bounds__(512, 2) void conv_mfma(const ushort_t* __restrict__ Xt,
                                                    const ushort_t* __restrict__ Wt,
                                                    const void* bias, float* __restrict__ out,
                                                    const int* flagp) {
    constexpr int RS = CI + 8;
    constexpr int SROWS = 195;
    constexpr int SBYTES = SROWS * RS * 2;
    constexpr int OBYTES = 128 * 68 * 4;
    constexpr int SMEM = SBYTES > OBYTES ? SBYTES : OBYTES;
    __shared__ __align__(16) char smem[SMEM];
    ushort_t* S = (ushort_t*)smem;
    float* Ob = (float*)smem;

    int t = threadIdx.x;
    int blk = blockIdx.x;
    int b = blk >> 6, y = blk & 63;
    int n0 = y << 6;

    constexpr int RQ = CI / 8;
    constexpr int CNT = SROWS * RQ;
    for (int i = t; i < CNT; i += 512) {
        int s = i / RQ;
        int c8 = (i - s * RQ) * 8;
        int tok = n0 + s - 65;
        uint4 v = {0u, 0u, 0u, 0u};
        if (s < 194 && (unsigned)tok < 4096u)
            v = *(const uint4*)(Xt + ((size_t)b * 4096 + tok) * CI + c8);
        *(uint4*)(S + (size_t)s * RS + c8) = v;
    }
    __syncthreads();

    int lane = t & 63, w = t >> 6;
    int li = lane & 15, q = lane >> 4;
    int px0 = 16 * (w & 3);
    int coh = 64 * (w >> 2);
    int x = px0 + li;

    f32x4 acc[4];
    #pragma unroll
    for (int T = 0; T < 4; T++) acc[T] = {0.f, 0.f, 0.f, 0.f};

    #pragma unroll
    for (int tap = 0; tap < 9; tap++) {
        int dy = tap / 3 - 1, dx = tap % 3 - 1;
        bool vx = (unsigned)(x + dx) < 64u;
        int srow = x + dy * 64 + dx + 65;
        int sr2 = vx ? srow : 194;
        #pragma unroll
        for (int ks = 0; ks < CI / 32; ks++) {
            bf16x8 a = *(const bf16x8*)(S + (size_t)sr2 * RS + ks * 32 + q * 8);
            #pragma unroll
            for (int T = 0; T < 4; T++) {
                int co = coh + 16 * T + li;
                bf16x8 bb = *(const bf16x8*)(Wt + ((size_t)co * 9 + tap) * CI + ks * 32 + q * 8);
                acc[T] = __builtin_amdgcn_mfma_f32_16x16x32_bf16(a, bb, acc[T], 0, 0, 0);
            }
        }
    }
    __syncthreads();

    int F = *flagp;
    #pragma unroll
    for (int T = 0; T < 4; T++) {
        int co = coh + 16 * T + li;
        float bv = F ? ((const float*)bias)[co] : b2f(((const ushort_t*)bias)[co]);
        #pragma unroll
        for (int rr = 0; rr < 4; rr++)
            Ob[(size_t)co * 68 + px0 + 4 * q + rr] = acc[T][rr] + bv;
    }
    __syncthreads();
    for (int i = t; i < 2048; i += 512) {
        int co = i >> 4, p4 = (i & 15) * 4;
        *(uint4*)(out + ((size_t)(b * 128 + co)) * 4096 + n0 + p4) =
            *(const uint4*)(Ob + (size_t)co * 68 + p4);
    }
}

// ---------------- LayerNorm reductions ----------------
__global__ __launch_bounds__(256) void ln_reduce1(const float* __restrict__ src,
                                                  float* __restrict__ part) {
    int t = threadIdx.x;
    size_t base = (size_t)blockIdx.x * 1024 + t * 4;
    float4 v = *(const float4*)(src + base);
    float s = v.x + v.y + v.z + v.w;
    float q = v.x * v.x + v.y * v.y + v.z * v.z + v.w * v.w;
    for (int off = 32; off > 0; off >>= 1) {
        s += __shfl_down(s, off, 64);
        q += __shfl_down(q, off, 64);
    }
    __shared__ float red[8];
    if ((t & 63) == 0) { red[(t >> 6) * 2] = s; red[(t >> 6) * 2 + 1] = q; }
    __syncthreads();
    if (t == 0) {
        s = red[0] + red[2] + red[4] + red[6];
        q = red[1] + red[3] + red[5] + red[7];
        part[blockIdx.x * 2] = s;
        part[blockIdx.x * 2 + 1] = q;
    }
}

__global__ __launch_bounds__(256) void ln_reduce2(const float* __restrict__ part,
                                                  float* __restrict__ der) {
    int b = blockIdx.x, t = threadIdx.x;
    float s = part[(b * 512 + t) * 2] + part[(b * 512 + 256 + t) * 2];
    float q = part[(b * 512 + t) * 2 + 1] + part[(b * 512 + 256 + t) * 2 + 1];
    for (int off = 32; off > 0; off >>= 1) {
        s += __shfl_down(s, off, 64);
        q += __shfl_down(q, off, 64);
    }
    __shared__ float red[8];
    if ((t & 63) == 0) { red[(t >> 6) * 2] = s; red[(t >> 6) * 2 + 1] = q; }
    __syncthreads();
    if (t == 0) {
        s = red[0] + red[2] + red[4] + red[6];
        q = red[1] + red[3] + red[5] + red[7];
        float mean = s * (1.f / (float)CN);
        float var = q * (1.f / (float)CN) - mean * mean;
        der[b * 2] = mean;
        der[b * 2 + 1] = rsqrtf(var + 1e-5f);
    }
}

// ---------------- LN apply + LeakyReLU ----------------
template <typename TEXT, typename TOD, int HT, int HD>
__device__ __forceinline__ void ln_body(const float* src, const TEXT* g, const TEXT* be,
                                        const float* der, ushort_t* outT, TOD* outD,
                                        float (*tile)[33]) {
    int b = blockIdx.z, c0 = blockIdx.y * 32, n0 = blockIdx.x * 32;
    float mean = der[b * 2], rstd = der[b * 2 + 1];
    int nx = threadIdx.x & 31, cy = threadIdx.x >> 5;
    #pragma unroll
    for (int s = 0; s < 4; s++) {
        int cl = cy + s * 8;
        int c = c0 + cl;
        size_t gi = (size_t)c * Nn + n0 + nx;
        float v = (src[(size_t)b * CN + gi] - mean) * rstd * getv(g, gi) + getv(be, gi);
        v = lrelu(v);
        if (HD) stv(outD + (size_t)b * CN + gi, v);
        tile[cl][nx] = v;
    }
    if (HT) {
        __syncthreads();
        #pragma unroll
        for (int s = 0; s < 4; s++) {
            int nl = cy + s * 8;
            int n = n0 + nl;
            int c = c0 + nx;
            outT[((size_t)b * Nn + n) * Cn + c] = f2b(tile[nx][nl]);
        }
    }
}

template <int HT, int HD, int DEXT>
__global__ __launch_bounds__(256) void ln_apply(const float* src, const void* g, const void* be,
                                                const float* der, ushort_t* outT, void* outD,
                                                long doff, const int* flagp) {
    __shared__ float tile[32][33];
    int F = *flagp;
    if (F) {
        if (DEXT && HD)
            ln_body<float, float, HT, HD>(src, (const float*)g, (const float*)be, der, outT,
                                          ((float*)outD) + doff, tile);
        else
            ln_body<float, ushort_t, HT, HD>(src, (const float*)g, (const float*)be, der, outT,
                                             ((ushort_t*)outD) + doff, tile);
    } else {
        ln_body<ushort_t, ushort_t, HT, HD>(src, (const ushort_t*)g, (const ushort_t*)be, der, outT,
                                            ((ushort_t*)outD) + doff, tile);
    }
}

// ---------------- small GEMM (VALU) ----------------
template <int ACT, int TRANS, typename TA, typename TW, typename TO>
__device__ __forceinline__ void gemm_body(const TA* A, const TW* W, const TW* bias, TO* out,
                                          int M, int K, int Rper,
                                          float (*As)[68], float (*Bs)[68]) {
    int m0 = blockIdx.x << 6, r0 = blockIdx.y << 6;
    int t = threadIdx.x, tx = t & 15, ty = t >> 4;
    int sr = t >> 2, sk = (t & 3) << 2;
    float acc[4][4] = {{0.f}};
    for (int kt = 0; kt < K; kt += 16) {
        float4 av = get4(A, (size_t)(r0 + sr) * K + kt + sk);
        float4 wv = get4(W, (size_t)(m0 + sr) * K + kt + sk);
        As[sk + 0][sr] = av.x; As[sk + 1][sr] = av.y;
        As[sk + 2][sr] = av.z; As[sk + 3][sr] = av.w;
        Bs[sk + 0][sr] = wv.x; Bs[sk + 1][sr] = wv.y;
        Bs[sk + 2][sr] = wv.z; Bs[sk + 3][sr] = wv.w;
        __syncthreads();
        #pragma unroll
        for (int kk = 0; kk < 16; kk++) {
            float4 a4 = *(const float4*)&As[kk][ty << 2];
            float4 b4 = *(const float4*)&Bs[kk][tx << 2];
            float aa[4] = {a4.x, a4.y, a4.z, a4.w};
            float bb[4] = {b4.x, b4.y, b4.z, b4.w};
            #pragma unroll
            for (int ii = 0; ii < 4; ii++)
                #pragma unroll
                for (int jj = 0; jj < 4; jj++)
                    acc[ii][jj] += aa[ii] * bb[jj];
        }
        __syncthreads();
    }
    float bv[4];
    #pragma unroll
    for (int jj = 0; jj < 4; jj++) bv[jj] = getv(bias, m0 + (tx << 2) + jj);
    #pragma unroll
    for (int ii = 0; ii < 4; ii++) {
        int r = r0 + (ty << 2) + ii;
        float v[4];
        #pragma unroll
        for (int jj = 0; jj < 4; jj++) {
            float x = acc[ii][jj] + bv[jj];
            if (ACT) x = lrelu(x);
            v[jj] = x;
        }
        if (TRANS) {
            int rb = r / Rper, ri = r % Rper;
            #pragma unroll
            for (int jj = 0; jj < 4; jj++) {
                int m = m0 + (tx << 2) + jj;
                stv(out + ((size_t)rb * M + m) * Rper + ri, v[jj]);
            }
        } else {
            #pragma unroll
            for (int jj = 0; jj < 4; jj++)
                stv(out + (size_t)r * M + m0 + (tx << 2) + jj, v[jj]);
        }
    }
}

template <int ACT, int TRANS, int AK, typename TO>
__global__ __launch_bounds__(256) void gemm_nt(const void* A, long aoff, const void* W,
                                               const void* bias, TO* out, int M, int K, int Rper,
                                               const int* flagp) {
    __shared__ float As[16][68];
    __shared__ float Bs[16][68];
    int F = *flagp;
    if (AK == 0) {
        if (F) gemm_body<ACT, TRANS>((const ushort_t*)A + aoff, (const float*)W, (const float*)bias, out, M, K, Rper, As, Bs);
        else   gemm_body<ACT, TRANS>((const ushort_t*)A + aoff, (const ushort_t*)W, (const ushort_t*)bias, out, M, K, Rper, As, Bs);
    } else if (AK == 1) {
        if (F) gemm_body<ACT, TRANS>((const float*)A + aoff, (const float*)W, (const float*)bias, out, M, K, Rper, As, Bs);
        else   gemm_body<ACT, TRANS>((const float*)A + aoff, (const ushort_t*)W, (const ushort_t*)bias, out, M, K, Rper, As, Bs);
    } else {
        if (F) gemm_body<ACT, TRANS>((const float*)A + aoff, (const float*)W, (const float*)bias, out, M, K, Rper, As, Bs);
        else   gemm_body<ACT, TRANS>((const ushort_t*)A + aoff, (const ushort_t*)W, (const ushort_t*)bias, out, M, K, Rper, As, Bs);
    }
}

// ---------------- f_i_3 stage 1: out1 -> A' bf16, k-tiled [64 kt][512 r][64 k], PRE-SWIZZLED --
// 16-B granule g within each row is stored at g^(r&7) so the GEMM can copy the tile
// LINEARLY with global_load_lds and read fragments with the same XOR (rule #21c).
__global__ __launch_bounds__(256) void a_convert(const void* src, long aoff, ushort_t* dst,
                                                 const int* flagp) {
    int F = *flagp;
    int gid = blockIdx.x * 256 + threadIdx.x;   // 262144 groups of 8 elements
    int r = gid >> 9;                           // 0..511 (row = b*128 + c)
    int n0 = (gid & 511) << 3;                  // 0..4095 step 8
    int gs = ((n0 >> 3) & 7) ^ (r & 7);         // swizzled 16-B granule
    size_t doff = ((size_t)(n0 >> 6) << 15) + ((size_t)r << 6) + ((size_t)gs << 3);
    if (F) {
        const float* s = (const float*)src + aoff + (size_t)r * 4096 + n0;
        *(uint4*)(dst + doff) = pack8(*(const float4*)s, *(const float4*)(s + 4));
    } else {
        const ushort_t* s = (const ushort_t*)src + aoff + (size_t)r * 4096 + n0;
        *(uint4*)(dst + doff) = *(const uint4*)s;
    }
}

// ---------------- f_i_3 stage 2: MFMA GEMM via global_load_lds, 128x128 tile, K-split 4 ------
// R8's gemm_big6 (128x64 tile) verified the gl_lds 2-barrier machinery (scratch gone,
// 554->522 total) but has HALF m97's arithmetic intensity: 16 MFMAs/wave per 32 KB staged.
// gemm_big7 widens to 128x128: 32 MFMAs/wave per 48 KB staged (A 16K + B-fp32 32K),
// staging-bytes/MFMA halves, fragment-reads/MFMA 1.0 -> 1.33. Grid (32 m, 4 rb, 4 ksl)
// = 512 blocks = 2/CU (LDS 48 KB). Same pre-swizzled A, same W3 row-XOR swizzle, same
// bf16 partials. Parameter change inheriting R8's verified structure.
template <int F>
__device__ __forceinline__ void gemm7_body(const ushort_t* __restrict__ Ap,
                                           const void* __restrict__ W3,
                                           ushort_t* __restrict__ Pc,
                                           char* smem) {
    int t = threadIdx.x;
    int m0 = blockIdx.x << 7;         // 128 output cols per block
    int rb = blockIdx.y;
    int ksl = blockIdx.z;
    int lane = t & 63, w = t >> 6;
    int li = lane & 15, q = lane >> 4;
    int wr = w & 1, wc = w >> 1;      // wave tile: rows 64*wr, cols 64*wc
    int kbase = ksl << 10;            // 1024 k-elements per split

    const char* Ab = (const char*)Ap;
    const char* Wb = (const char*)W3;
    size_t Abase = ((size_t)(ksl * 16) << 16) + ((size_t)rb << 14);

    f32x4 acc[4][4];
    #pragma unroll
    for (int i = 0; i < 4; i++)
        #pragma unroll
        for (int j = 0; j < 4; j++) acc[i][j] = {0.f, 0.f, 0.f, 0.f};

    // ---- async staging: no VGPR intermediates ----
    auto stageA = [&](int kt64) {
        size_t tb = Abase + ((size_t)kt64 << 16);
        #pragma unroll
        for (int i = 0; i < 4; i++) {
            int loff = w * 4096 + i * 1024;
            __builtin_amdgcn_global_load_lds(
                (const uint_t*)(Ab + tb + loff + lane * 16),
                (uint_t*)(smem + loff), 16, 0, 0);
        }
    };
    auto stageB = [&](int kt) {
        if (F) {
            // B tile 128 rows x 64 k fp32 = 32 KB; row = 256 B; 32-B granule XOR (row&7)
            #pragma unroll
            for (int i = 0; i < 8; i++) {
                int loff = w * 8192 + i * 1024;
                int L = loff + lane * 16;
                int row = L >> 8, inner = L & 255;
                int sg = (inner >> 5) ^ (row & 7);
                __builtin_amdgcn_global_load_lds(
                    (const uint_t*)(Wb + ((size_t)(m0 + row) << 14) +
                                    (size_t)(kbase + kt) * 4 + (sg << 5) + (inner & 31)),
                    (uint_t*)(smem + 16384 + loff), 16, 0, 0);
            }
        } else {
            // B tile 128 rows x 64 k bf16 = 16 KB; row = 128 B; 16-B granule XOR (row&7)
            #pragma unroll
            for (int i = 0; i < 4; i++) {
                int loff = w * 4096 + i * 1024;
                int L = loff + lane * 16;
                int row = L >> 7, inner = L & 127;
                int sg = (inner >> 4) ^ (row & 7);
                __builtin_amdgcn_global_load_lds(
                    (const uint_t*)(Wb + ((size_t)(m0 + row) << 13) +
                                    (size_t)(kbase + kt) * 2 + (sg << 4)),
                    (uint_t*)(smem + 16384 + loff), 16, 0, 0);
            }
        }
    };

    stageA(0);
    stageB(0);
    for (int it = 0; it < 16; it++) {
        __syncthreads();               // staging landed for all waves
        const ushort_t* As = (const ushort_t*)smem;
        #pragma unroll
        for (int ks = 0; ks < 2; ks++) {
            int gsw = ks * 4 + q;
            int sw = (gsw ^ (li & 7)) << 3;
            bf16x8 af[4], bfr[4];
            #pragma unroll
            for (int rf = 0; rf < 4; rf++) {
                int row = 64 * wr + 16 * rf + li;
                af[rf] = *(const bf16x8*)(As + row * 64 + sw);
            }
            if (F) {
                const float* Bf = (const float*)(smem + 16384);
                #pragma unroll
                for (int cf = 0; cf < 4; cf++) {
                    int row = 64 * wc + 16 * cf + li;
                    const float* p = Bf + row * 64 + sw;
                    float4 lo = *(const float4*)p;
                    float4 hi = *(const float4*)(p + 4);
                    bf16x8 v;
                    v[0] = (__bf16)lo.x; v[1] = (__bf16)lo.y;
                    v[2] = (__bf16)lo.z; v[3] = (__bf16)lo.w;
                    v[4] = (__bf16)hi.x; v[5] = (__bf16)hi.y;
                    v[6] = (__bf16)hi.z; v[7] = (__bf16)hi.w;
                    bfr[cf] = v;
                }
            } else {
                const ushort_t* Bs = (const ushort_t*)(smem + 16384);
                #pragma unroll
                for (int cf = 0; cf < 4; cf++) {
                    int row = 64 * wc + 16 * cf + li;
                    bfr[cf] = *(const bf16x8*)(Bs + row * 64 + sw);
                }
            }
            #pragma unroll
            for (int rf = 0; rf < 4; rf++)
                #pragma unroll
                for (int cf = 0; cf < 4; cf++)
                    acc[rf][cf] = __builtin_amdgcn_mfma_f32_16x16x32_bf16(af[rf], bfr[cf], acc[rf][cf], 0, 0, 0);
        }
        __syncthreads();               // all reads of this tile done
        if (it < 15) {
            stageA(it + 1);
            stageB((it + 1) << 6);
        }
    }

    // epilogue: acc -> LDS bf16 tile [128][136] -> coalesced bf16 partial write
    // 128 rows x 128 cols, uint4 = 8 cols/store -> row = idx>>4, c8 = (idx&15)*8
    ushort_t* Ot = (ushort_t*)smem;
    #pragma unroll
    for (int rf = 0; rf < 4; rf++)
        #pragma unroll
        for (int cf = 0; cf < 4; cf++)
            #pragma unroll
            for (int rr = 0; rr < 4; rr++)
                Ot[(64 * wr + 16 * rf + 4 * q + rr) * 136 + 64 * wc + 16 * cf + li] =
                    f2b(acc[rf][cf][rr]);
    __syncthreads();
    #pragma unroll
    for (int i = 0; i < 8; i++) {
        int idx = t + i * 256;
        int row = idx >> 4, c8 = (idx & 15) * 8;
        *(uint4*)(Pc + ((size_t)(rb * 128 + row)) * 4096 + m0 + c8) =
            *(const uint4*)(Ot + row * 136 + c8);
    }
}

__global__ __launch_bounds__(256, 2) void gemm_big7(const ushort_t* __restrict__ Ap,
                                                    const void* __restrict__ W3,
                                                    ushort_t* __restrict__ C0,
                                                    ushort_t* __restrict__ C1,
                                                    ushort_t* __restrict__ C2,
                                                    ushort_t* __restrict__ C3,
                                                    const int* flagp) {
    __shared__ __align__(16) char smem[49152];
    int F = *flagp;
    int ksl = blockIdx.z;
    ushort_t* Pc = (ksl == 0) ? C0 : (ksl == 1) ? C1 : (ksl == 2) ? C2 : C3;
    if (F) gemm7_body<1>(Ap, W3, Pc, smem);
    else   gemm7_body<0>(Ap, W3, Pc, smem);
}

// ---------------- f_i_3 stage 3: merge 4 bf16 K-split partials + bias + lrelu -> (b,m,c) bf16 --
__global__ __launch_bounds__(256) void gemm_merge(const ushort_t* __restrict__ C0,
                                                  const ushort_t* __restrict__ C1,
                                                  const ushort_t* __restrict__ C2,
                                                  const ushort_t* __restrict__ C3,
                                                  const void* b3, ushort_t* __restrict__ out,
                                                  const int* flagp) {
    __shared__ float tile[32][33];
    int F = *flagp;
    int m0 = blockIdx.x * 32, c0 = blockIdx.y * 32, b = blockIdx.z;
    int nx = threadIdx.x & 31, cy = threadIdx.x >> 5;
    float bv = F ? ((const float*)b3)[m0 + nx] : b2f(((const ushort_t*)b3)[m0 + nx]);
    #pragma unroll
    for (int s = 0; s < 4; s++) {
        int cl = cy + s * 8;
        size_t ri = (size_t)(b * 128 + c0 + cl) * 4096 + m0 + nx;
        tile[cl][nx] = lrelu(b2f(C0[ri]) + b2f(C1[ri]) + b2f(C2[ri]) + b2f(C3[ri]) + bv);
    }
    __syncthreads();
    #pragma unroll
    for (int s = 0; s < 4; s++) {
        int ml = cy + s * 8;
        out[((size_t)b * 4096 + m0 + ml) * 128 + c0 + nx] = f2b(tile[nx][ml]);
    }
}

// ---------------- MFMA flash attention v3 ----------------
// KV-split 4-way; each block: 128 Q-rows, 16 KV tiles; each WAVE owns 32 Q-rows
// (2 sub-blocks of 16) so every Ks/Vt b128 fragment read feeds 2 MFMAs.
__global__ __launch_bounds__(256, 2) void attn_mfma(const ushort_t* __restrict__ Q,
                                                    const ushort_t* __restrict__ Kg,
                                                    const ushort_t* __restrict__ Vg,
                                                    ushort_t* __restrict__ Op0,
                                                    ushort_t* __restrict__ Op1,
                                                    ushort_t* __restrict__ Op2,
                                                    ushort_t* __restrict__ Op3,
                                                    float* __restrict__ ML) {
    __shared__ __align__(16) ushort_t Ks[64 * 136];
    __shared__ __align__(16) ushort_t Vt[128 * 72];
    __shared__ __align__(16) ushort_t Ps[128 * 88];

    int t = threadIdx.x;
    int blk = blockIdx.x;
    int h = blk >> 7;            // KV split 0..3
    int rblk = blk & 127;
    int b = rblk & 3;
    int qt = rblk >> 2;          // 0..31
    int n0 = qt << 7;            // 128 Q rows per block
    int lane = t & 63, w = t >> 6;
    int li = lane & 15, q = lane >> 4;

    int kj = t >> 2, kc0 = (t & 3) * 32;
    int vd = t >> 1, vk0 = (t & 1) * 32;

    int kt0 = h << 4;            // first KV tile (16 per split)
    int m00 = kt0 << 6;

    {   // stage K first
        const ushort_t* kp = Kg + ((size_t)(b * Nn + m00 + kj)) * 128 + kc0;
        ushort_t* dst = Ks + kj * 136 + kc0;
        #pragma unroll
        for (int cc = 0; cc < 4; cc++)
            *(uint4*)(dst + cc * 8) = *(const uint4*)(kp + cc * 8);
    }
    {   // stage V first
        const ushort_t* vp = Vg + (size_t)b * CN + (size_t)vd * Nn + m00 + vk0;
        ushort_t* dst = Vt + vd * 72 + vk0;
        #pragma unroll
        for (int cc = 0; cc < 4; cc++)
            *(uint4*)(dst + cc * 8) = *(const uint4*)(vp + cc * 8);
    }

    // Q fragments straight from global (one-time; rows 32w+16sub+li)
    bf16x8 qf[2][4];
    #pragma unroll
    for (int sub = 0; sub < 2; sub++)
        #pragma unroll
        for (int ks = 0; ks < 4; ks++)
            qf[sub][ks] = *(const bf16x8*)(Q +
                ((size_t)(b * Nn + n0 + 32 * w + 16 * sub + li)) * 128 + ks * 32 + q * 8);

    f32x4 acc[2][8];
    #pragma unroll
    for (int sub = 0; sub < 2; sub++)
        #pragma unroll
        for (int T = 0; T < 8; T++) acc[sub][T] = {0.f, 0.f, 0.f, 0.f};
    float m_i[2][4], l_i[2][4];   // l_i LANE-PARTIAL (reduced once at the end)
    #pragma unroll
    for (int sub = 0; sub < 2; sub++)
        #pragma unroll
        for (int r = 0; r < 4; r++) { m_i[sub][r] = -1e30f; l_i[sub][r] = 0.f; }

    __syncthreads();

    for (int kt = kt0; kt < kt0 + 16; kt++) {
        uint4 pk[4], pv[4];
        bool pf = kt < kt0 + 15;
        if (pf) {
            int m1 = (kt + 1) << 6;
            const ushort_t* kp = Kg + ((size_t)(b * Nn + m1 + kj)) * 128 + kc0;
            #pragma unroll
            for (int cc = 0; cc < 4; cc++) pk[cc] = *(const uint4*)(kp + cc * 8);
            const ushort_t* vp = Vg + (size_t)b * CN + (size_t)vd * Nn + m1 + vk0;
            #pragma unroll
            for (int cc = 0; cc < 4; cc++) pv[cc] = *(const uint4*)(vp + cc * 8);
        }

        // S = Q . K^T for both sub-blocks; each Ks fragment feeds 2 MFMAs
        f32x4 s[2][4];
        #pragma unroll
        for (int sub = 0; sub < 2; sub++)
            #pragma unroll
            for (int T = 0; T < 4; T++) s[sub][T] = {0.f, 0.f, 0.f, 0.f};
        __builtin_amdgcn_s_setprio(1);
        #pragma unroll
        for (int ks = 0; ks < 4; ks++) {
            bf16x8 a0 = qf[0][ks];
            bf16x8 a1 = qf[1][ks];
            #pragma unroll
            for (int T = 0; T < 4; T++) {
                bf16x8 kb = *(const bf16x8*)(Ks + (16 * T + li) * 136 + ks * 32 + q * 8);
                s[0][T] = __builtin_amdgcn_mfma_f32_16x16x32_bf16(a0, kb, s[0][T], 0, 0, 0);
                s[1][T] = __builtin_amdgcn_mfma_f32_16x16x32_bf16(a1, kb, s[1][T], 0, 0, 0);
            }
        }
        __builtin_amdgcn_s_setprio(0);

        // online softmax, rows (32w + 16sub + 4q + r), wave-local
        float rm[2][4];
        bool grow = false;
        #pragma unroll
        for (int sub = 0; sub < 2; sub++)
            #pragma unroll
            for (int r = 0; r < 4; r++) {
                float v = fmaxf(fmaxf(s[sub][0][r], s[sub][1][r]),
                                fmaxf(s[sub][2][r], s[sub][3][r]));
                v = fmaxf(v, __shfl_xor(v, 1, 64));
                v = fmaxf(v, __shfl_xor(v, 2, 64));
                v = fmaxf(v, __shfl_xor(v, 4, 64));
                v = fmaxf(v, __shfl_xor(v, 8, 64));
                rm[sub][r] = v;
                grow = grow || (v > m_i[sub][r]);
            }
        if (__any(grow)) {
            #pragma unroll
            for (int sub = 0; sub < 2; sub++)
                #pragma unroll
                for (int r = 0; r < 4; r++) {
                    float mnew = fmaxf(m_i[sub][r], rm[sub][r]);
                    float al = __expf(m_i[sub][r] - mnew);
                    m_i[sub][r] = mnew;
                    float rsum = 0.f;
                    #pragma unroll
                    for (int T = 0; T < 4; T++) {
                        float pvv = __expf(s[sub][T][r] - mnew);
                        Ps[(32 * w + 16 * sub + 4 * q + r) * 88 + 16 * T + li] = f2b(pvv);
                        rsum += pvv;
                    }
                    l_i[sub][r] = l_i[sub][r] * al + rsum;
                    #pragma unroll
                    for (int T = 0; T < 8; T++) acc[sub][T][r] *= al;
                }
        } else {
            #pragma unroll
            for (int sub = 0; sub < 2; sub++)
                #pragma unroll
                for (int r = 0; r < 4; r++) {
                    float rsum = 0.f;
                    #pragma unroll
                    for (int T = 0; T < 4; T++) {
                        float pvv = __expf(s[sub][T][r] - m_i[sub][r]);
                        Ps[(32 * w + 16 * sub + 4 * q + r) * 88 + 16 * T + li] = f2b(pvv);
                        rsum += pvv;
                    }
                    l_i[sub][r] += rsum;
                }
        }

        // O += P . V ; each Vt fragment feeds 2 MFMAs
        __builtin_amdgcn_s_setprio(1);
        #pragma unroll
        for (int ks = 0; ks < 2; ks++) {
            bf16x8 pa0 = *(const bf16x8*)(Ps + (32 * w + li) * 88 + ks * 32 + q * 8);
            bf16x8 pa1 = *(const bf16x8*)(Ps + (32 * w + 16 + li) * 88 + ks * 32 + q * 8);
            #pragma unroll
            for (int T = 0; T < 8; T++) {
                bf16x8 vb = *(const bf16x8*)(Vt + (16 * T + li) * 72 + ks * 32 + q * 8);
                acc[0][T] = __builtin_amdgcn_mfma_f32_16x16x32_bf16(pa0, vb, acc[0][T], 0, 0, 0);
                acc[1][T] = __builtin_amdgcn_mfma_f32_16x16x32_bf16(pa1, vb, acc[1][T], 0, 0, 0);
            }
        }
        __builtin_amdgcn_s_setprio(0);
        __syncthreads();
        if (pf) {
            ushort_t* dk = Ks + kj * 136 + kc0;
            #pragma unroll
            for (int cc = 0; cc < 4; cc++) *(uint4*)(dk + cc * 8) = pk[cc];
            ushort_t* dv = Vt + vd * 72 + vk0;
            #pragma unroll
            for (int cc = 0; cc < 4; cc++) *(uint4*)(dv + cc * 8) = pv[cc];
            __syncthreads();
        }
    }

    // reduce lane-partial l across the 16-lane row group (once)
    #pragma unroll
    for (int sub = 0; sub < 2; sub++)
        #pragma unroll
        for (int r = 0; r < 4; r++) {
            float ls = l_i[sub][r];
            ls += __shfl_xor(ls, 1, 64);
            ls += __shfl_xor(ls, 2, 64);
            ls += __shfl_xor(ls, 4, 64);
            ls += __shfl_xor(ls, 8, 64);
            l_i[sub][r] = ls;
        }

    // emit unnormalized partials (bf16) + (m,l)
    ushort_t* Op = (h == 0) ? Op0 : (h == 1) ? Op1 : (h == 2) ? Op2 : Op3;
    #pragma unroll
    for (int sub = 0; sub < 2; sub++)
        #pragma unroll
        for (int T = 0; T < 8; T++)
            #pragma unroll
            for (int r = 0; r < 4; r++) {
                int n = n0 + 32 * w + 16 * sub + 4 * q + r;
                int d = 16 * T + li;
                Op[((size_t)(b * Nn + n)) * 128 + d] = f2b(acc[sub][T][r]);
            }
    if (li == 0) {
        #pragma unroll
        for (int sub = 0; sub < 2; sub++)
            #pragma unroll
            for (int r = 0; r < 4; r++) {
                int n = n0 + 32 * w + 16 * sub + 4 * q + r;
                size_t mi = ((size_t)(h * Bn + b) * Nn + n) * 2;
                ML[mi] = m_i[sub][r];
                ML[mi + 1] = l_i[sub][r];
            }
    }
}

// ---------------- attention merge: combine 4 KV-split partials -> fp32 (b,n,c) ----------------
__global__ __launch_bounds__(256) void attn_merge(const ushort_t* __restrict__ Op0,
                                                  const ushort_t* __restrict__ Op1,
                                                  const ushort_t* __restrict__ Op2,
                                                  const ushort_t* __restrict__ Op3,
                                                  const float* __restrict__ ML,
                                                  float* __restrict__ Og) {
    int idx = blockIdx.x * 256 + threadIdx.x;   // 262144 items: token*16 + c8grp
    int token = idx >> 4;
    int c8 = (idx & 15) * 8;
    float m[4], l[4];
    #pragma unroll
    for (int s = 0; s < 4; s++) {
        m[s] = ML[((size_t)s * (Bn * Nn) + token) * 2];
        l[s] = ML[((size_t)s * (Bn * Nn) + token) * 2 + 1];
    }
    float M = fmaxf(fmaxf(m[0], m[1]), fmaxf(m[2], m[3]));
    float e[4];
    float denom = 0.f;
    #pragma unroll
    for (int s = 0; s < 4; s++) { e[s] = __expf(m[s] - M); denom += l[s] * e[s]; }
    float inv = 1.f / denom;
    #pragma unroll
    for (int s = 0; s < 4; s++) e[s] *= inv;
    uint4 u0 = *(const uint4*)(Op0 + (size_t)token * 128 + c8);
    uint4 u1 = *(const uint4*)(Op1 + (size_t)token * 128 + c8);
    uint4 u2 = *(const uint4*)(Op2 + (size_t)token * 128 + c8);
    uint4 u3 = *(const uint4*)(Op3 + (size_t)token * 128 + c8);
    float f0[8], f1[8], f2[8], f3[8];
    unpack8(u0, f0);
    unpack8(u1, f1);
    unpack8(u2, f2);
    unpack8(u3, f3);
    float o[8];
    #pragma unroll
    for (int j = 0; j < 8; j++)
        o[j] = f0[j] * e[0] + f1[j] * e[1] + f2[j] * e[2] + f3[j] * e[3];
    float4 v0 = {o[0], o[1], o[2], o[3]};
    float4 v1 = {o[4], o[5], o[6], o[7]};
    float* op = Og + (size_t)token * 128 + c8;
    *(float4*)op = v0;
    *(float4*)(op + 4) = v1;
}

// ---------------- final: f_e_8 = conv1x1(f_e_5 * f_i_6, wf) + bf ----------------
template <typename TEXT, typename TOUT>
__device__ __forceinline__ void final_body(const ushort_t* fe5, const ushort_t* fi6t,
                                           const TEXT* wf, const TEXT* bf, TOUT* out0,
                                           float* prod, ushort_t* wfs, float* bfs) {
    int t = threadIdx.x;
    int b = blockIdx.x >> 6;
    int px0 = (blockIdx.x & 63) * 64;
    for (int idx = t * 4; idx < 8192; idx += 1024) {
        float4 v = get4(wf, idx);
        ushort4 u = {f2b(v.x), f2b(v.y), f2b(v.z), f2b(v.w)};
        *(ushort4*)&wfs[idx] = u;
    }
    if (t < 64) bfs[t] = getv(bf, t);
    {
        int pix = t >> 2, kc = (t & 3) * 32;
        const ushort_t* ap = fe5 + ((size_t)(b * Nn + px0 + pix)) * 128 + kc;
        const ushort_t* bp = fi6t + ((size_t)(b * Nn + px0 + pix)) * 128 + kc;
        #pragma unroll
        for (int c = 0; c < 4; c++) {
            uint4 ua = *(const uint4*)(ap + c * 8);
            uint4 ub = *(const uint4*)(bp + c * 8);
            float fa[8], fb[8];
            unpack8(ua, fa);
            unpack8(ub, fb);
            float* pp = &prod[pix * 132 + kc + c * 8];
            #pragma unroll
            for (int j = 0; j < 8; j++) pp[j] = fa[j] * fb[j];
        }
    }
    __syncthreads();
    int pix = t >> 2, og = t & 3;
    for (int k = 0; k < 16; k++) {
        int o = og * 16 + k;
        float a = bfs[o];
        for (int kc = 0; kc < 128; kc += 8) {
            uint4 wu = *(const uint4*)&wfs[o * 128 + kc];
            float w8[8];
            unpack8(wu, w8);
            const float* pp = &prod[pix * 132 + kc];
            float4 p0 = *(const float4*)pp;
            float4 p1 = *(const float4*)(pp + 4);
            a += w8[0] * p0.x + w8[1] * p0.y + w8[2] * p0.z + w8[3] * p0.w
               + w8[4] * p1.x + w8[5] * p1.y + w8[6] * p1.z + w8[7] * p1.w;
        }
        stv(out0 + ((size_t)(b * 64 + o)) * Nn + px0 + pix, a);
    }
}

__global__ __launch_bounds__(256) void final_out(const ushort_t* fe5, const ushort_t* fi6t,
                                                 const void* wf, const void* bf, void* out0,
                                                 const int* flagp) {
    __shared__ __align__(16) float prod[64 * 132];
    __shared__ __align__(16) ushort_t wfs[64 * 128];
    __shared__ float bfs[64];
    int F = *flagp;
    if (F) final_body((const ushort_t*)fe5, fi6t, (const float*)wf, (const float*)bf, (float*)out0, prod, wfs, bfs);
    else   final_body((const ushort_t*)fe5, fi6t, (const ushort_t*)wf, (const ushort_t*)bf, (ushort_t*)out0, prod, wfs, bfs);
}

extern "C" void kernel_launch(void* const* d_in, const int* in_sizes, int n_in,
                              void* d_out, int out_size, void* d_ws, size_t ws_size,
                              hipStream_t stream) {
    const void* f_e = d_in[0];
    const void* f_i = d_in[1];
    const void* w1 = d_in[2];
    const void* b1 = d_in[3];
    const void* g1 = d_in[4];
    const void* be1 = d_in[5];
    const void* w2 = d_in[6];
    const void* b2 = d_in[7];
    const void* g2 = d_in[8];
    const void* be2 = d_in[9];
    const void* W3 = d_in[10];
    const void* b3 = d_in[11];
    const void* W4 = d_in[12];
    const void* b4 = d_in[13];
    const void* W5 = d_in[14];
    const void* b5 = d_in[15];
    const void* w6a = d_in[16];
    const void* b6a = d_in[17];
    const void* g6a = d_in[18];
    const void* be6a = d_in[19];
    const void* w6b = d_in[20];
    const void* b6b = d_in[21];
    const void* g6b = d_in[22];
    const void* be6b = d_in[23];
    const void* wf = d_in[24];
    const void* bf = d_in[25];

    char* wsb = (char*)d_ws;
    int* FLAG = (int*)wsb;
    float* PART = (float*)(wsb + 1024);
    float* DER  = (float*)(wsb + 17408);
    ushort_t* Wt1  = (ushort_t*)(wsb + 32768);
    ushort_t* Wt2  = (ushort_t*)(wsb + 180224);
    ushort_t* Wt6b = (ushort_t*)(wsb + 327680);
    float* ML   = (float*)(wsb + 32768);         // 512 KB (4 splits), reuses dead Wt1/Wt2 at attn time
    float* TMP  = (float*)(wsb + 622592);
    ushort_t* FE1  = (ushort_t*)(wsb + 9011200);
    ushort_t* TOK  = FE1 + BUF;
    ushort_t* FI3T = TOK + BUF;
    ushort_t* FE4  = FI3T + BUF;
    ushort_t* Y6   = FE4 + BUF;
    ushort_t* FI6T = Y6 + BUF;

    ushort_t* FEt = FI3T;
    ushort_t* FIt = FE4;

    // f_i_3 scratch (all dead at gemm_big7 time):
    // bf16 K-split partials [512 r][4096 m] x4: C0b/C1b in TMP (8 MB), C2b=FE4, C3b=Y6;
    // A' bf16 (k-tiled, pre-swizzled) in FI6T
    ushort_t* C0b = (ushort_t*)TMP;
    ushort_t* C1b = C0b + BUF;
    ushort_t* C2b = FE4;
    ushort_t* C3b = Y6;
    ushort_t* ABF = FI6T;

    // attention scratch: partials 2/3 in the dead TMP region; merged fp32 output
    // in the dead K/Q buffers (FI3T+FE4, 8 MB contiguous)
    ushort_t* OPA = (ushort_t*)TMP;
    ushort_t* OPB = OPA + BUF;
    float* MRG = (float*)FI3T;

    const long OUT1OFF = (long)Bn * IND * Nn;

    dim3 lnGrid(128, 4, 4);
    dim3 tinGrid(128, 2, 4);

    detect_kernel<<<1, 64, 0, stream>>>(g1, FLAG);

    wtrans<64><<<288, 256, 0, stream>>>(w1, Wt1, FLAG);
    wtrans<64><<<288, 256, 0, stream>>>(w2, Wt2, FLAG);
    wtrans<128><<<576, 256, 0, stream>>>(w6b, Wt6b, FLAG);

    // f_1: transpose -> conv(MFMA) -> LN -> FE1 (b,c,n)
    transpose_in<<<tinGrid, 256, 0, stream>>>(f_e, FEt, FLAG);
    conv_mfma<64><<<256, 512, 0, stream>>>(FEt, Wt1, b1, TMP, FLAG);
    ln_reduce1<<<2048, 256, 0, stream>>>(TMP, PART);
    ln_reduce2<<<4, 256, 0, stream>>>(PART, DER);
    ln_apply<0, 1, 0><<<lnGrid, 256, 0, stream>>>(TMP, g1, be1, DER, nullptr, FE1, 0, FLAG);

    // f_2: transpose -> conv(MFMA) -> LN -> TOK (b,n,c) + out1 (b,c,n ext)
    transpose_in<<<tinGrid, 256, 0, stream>>>(f_i, FIt, FLAG);
    conv_mfma<64><<<256, 512, 0, stream>>>(FIt, Wt2, b2, TMP, FLAG);
    ln_reduce1<<<2048, 256, 0, stream>>>(TMP, PART);
    ln_reduce2<<<4, 256, 0, stream>>>(PART, DER);
    ln_apply<1, 1, 1><<<lnGrid, 256, 0, stream>>>(TMP, g2, be2, DER, TOK, d_out, OUT1OFF, FLAG);

    // f_i_3: convert A -> bf16 (k-tiled, pre-swizzled), gl_lds MFMA GEMM 128x128 tile
    // (K-split 4, 512 blocks = 2/CU), merge 4 bf16 partials -> FI3T
    a_convert<<<1024, 256, 0, stream>>>(d_out, OUT1OFF, ABF, FLAG);
    gemm_big7<<<dim3(32, 4, 4), 256, 0, stream>>>(ABF, W3, C0b, C1b, C2b, C3b, FLAG);
    gemm_merge<<<dim3(128, 4, 4), 256, 0, stream>>>(C0b, C1b, C2b, C3b, b3, FI3T, FLAG);

    // f_e_4: TOK -> FE4
    gemm_nt<1, 0, 0, ushort_t><<<dim3(2, 256), 256, 0, stream>>>(TOK, 0, W4, b4, FE4, 128, 128, 1, FLAG);

    // f_6a: conv1x1 -> TMP (b,c,n) -> LN -> Y6 (b,n,c)
    gemm_nt<0, 1, 0, float><<<dim3(2, 256), 256, 0, stream>>>(TOK, 0, w6a, b6a, TMP, 128, 128, 4096, FLAG);
    ln_reduce1<<<2048, 256, 0, stream>>>(TMP, PART);
    ln_reduce2<<<4, 256, 0, stream>>>(PART, DER);
    ln_apply<1, 0, 0><<<lnGrid, 256, 0, stream>>>(TMP, g6a, be6a, DER, Y6, nullptr, 0, FLAG);

    // f_6b: conv(MFMA) -> LN -> FI6T (b,n,c)
    conv_mfma<128><<<256, 512, 0, stream>>>(Y6, Wt6b, b6b, TMP, FLAG);
    ln_reduce1<<<2048, 256, 0, stream>>>(TMP, PART);
    ln_reduce2<<<4, 256, 0, stream>>>(PART, DER);
    ln_apply<1, 0, 0><<<lnGrid, 256, 0, stream>>>(TMP, g6b, be6b, DER, FI6T, nullptr, 0, FLAG);

    // attention: 4-way KV-split partials (TOK, Y6, TMP region — all dead) + ML,
    // then merge -> MRG (fp32, in dead FI3T+FE4)
    attn_mfma<<<512, 256, 0, stream>>>(FE4, FI3T, FE1, TOK, Y6, OPA, OPB, ML);
    attn_merge<<<1024, 256, 0, stream>>>(TOK, Y6, OPA, OPB, ML, MRG);

    // f_e_5: MRG (fp32) -> Y6 (b,n,c) bf16
    gemm_nt<1, 0, 1, ushort_t><<<dim3(2, 256), 256, 0, stream>>>(MRG, 0, W5, b5, Y6, 128, 128, 1, FLAG);

    // final
    final_out<<<256, 256, 0, stream>>>(Y6, FI6T, wf, bf, d_out, FLAG);
}